// Round 12
// baseline (5010.229 us; speedup 1.0000x reference)
//
#include <hip/hip_runtime.h>

typedef unsigned short u16;
typedef unsigned int u32;
typedef unsigned long long u64;
typedef __bf16 bf16x8 __attribute__((ext_vector_type(8)));
typedef float f32x4 __attribute__((ext_vector_type(4)));

__device__ __forceinline__ float bf2f(u16 u) { return __uint_as_float(((u32)u) << 16); }
__device__ __forceinline__ u16 f2bf(float f) {
    u32 u = __float_as_uint(f);
    u32 r = (u + 0x7FFFu + ((u >> 16) & 1u)) >> 16;
    return (u16)r;
}
__device__ __forceinline__ float sigm(float x) { return 1.0f / (1.0f + __expf(-x)); }
__device__ __forceinline__ float elu1(float x) { return x > 0.0f ? x + 1.0f : __expf(x); }

// Zero-cost intra-wave phase fence (R16-validated)
__device__ __forceinline__ void wb() { __builtin_amdgcn_wave_barrier(); }

// agent-scope (LLC) atomics — HW-validated cross-XCD path (R5/R7/R13)
__device__ __forceinline__ int ag_load(const int* p) {
    return __hip_atomic_load(p, __ATOMIC_RELAXED, __HIP_MEMORY_SCOPE_AGENT);
}
__device__ __forceinline__ void ag_store(int* p, int v) {
    __hip_atomic_store(p, v, __ATOMIC_RELAXED, __HIP_MEMORY_SCOPE_AGENT);
}
__device__ __forceinline__ void ag_storef(float* p, float v) {
    __hip_atomic_store(p, v, __ATOMIC_RELAXED, __HIP_MEMORY_SCOPE_AGENT);
}
__device__ __forceinline__ void llc_store2(u16* p, u16 a, u16 b) {
    u32 v = (u32)a | ((u32)b << 16);
    __hip_atomic_store((u32*)p, v, __ATOMIC_RELAXED, __HIP_MEMORY_SCOPE_AGENT);
}
__device__ __forceinline__ void llc_store_u16(u16* p, u16 v) {
    __hip_atomic_store(p, v, __ATOMIC_RELAXED, __HIP_MEMORY_SCOPE_AGENT);
}

// ---------------------------------------------------------------------------
struct Cvt8 { const float* s[8]; u16* d[8]; int off4[9]; };

__global__ __launch_bounds__(256) void k_f2b8(Cvt8 c)
{
    int i = blockIdx.x * 256 + threadIdx.x;
    if (i >= c.off4[8]) return;
    int k = 0;
#pragma unroll
    for (int q = 1; q < 8; q++) if (i >= c.off4[q]) k = q;
    int j = i - c.off4[k];
    float4 v = ((const float4*)c.s[k])[j];
    ushort4 o;
    o.x = f2bf(v.x); o.y = f2bf(v.y); o.z = f2bf(v.z); o.w = f2bf(v.w);
    ((ushort4*)c.d[k])[j] = o;
}

// ---------------------------------------------------------------------------
__global__ __launch_bounds__(256) void k_embed(const int* __restrict__ tok,
                                               const float* __restrict__ W,
                                               u16* __restrict__ out)
{
    int c = blockIdx.x * 256 + threadIdx.x;
    int row = c >> 5, cc = (c & 31) * 8;
    int t = tok[row];
    const float* src = W + (size_t)t * 256 + cc;
    u16 tmp[8];
#pragma unroll
    for (int k = 0; k < 8; k++) tmp[k] = f2bf(src[k]);
    *(uint4*)(out + (size_t)row * 256 + cc) = *(uint4*)tmp;
}

// ---------------------------------------------------------------------------
// GEMM:  C[M,N] = A[M,K](bf16, lda) * B[N,K]^T(bf16) + bias. 128x128 tile.
// ---------------------------------------------------------------------------
__global__ __launch_bounds__(256) void k_gemm_bt(
    const u16* __restrict__ A, int lda,
    const u16* __restrict__ B,
    u16* __restrict__ Cb, float* __restrict__ Cf, int ldc,
    const float* __restrict__ bias1, const float* __restrict__ bias2,
    int N, int K)
{
    __shared__ u16 As[128][40];
    __shared__ u16 Bs[128][40];
    const int tid = threadIdx.x;
    const int m0 = blockIdx.x * 128, n0 = blockIdx.y * 128;
    const int wave = tid >> 6, lane = tid & 63;
    const int wm = wave & 1, wn = wave >> 1;
    const int quad = lane >> 4, l16 = lane & 15;
    f32x4 acc[4][4] = {};
    for (int k0 = 0; k0 < K; k0 += 32) {
        __syncthreads();
#pragma unroll
        for (int i = 0; i < 2; i++) {
            int c = tid + i * 256, row = c >> 2, cc = (c & 3) * 8;
            *(uint4*)(&As[row][cc]) = *(const uint4*)(A + (size_t)(m0 + row) * lda + k0 + cc);
            uint4 d = {0, 0, 0, 0};
            if (n0 + row < N) d = *(const uint4*)(B + (size_t)(n0 + row) * K + k0 + cc);
            *(uint4*)(&Bs[row][cc]) = d;
        }
        __syncthreads();
        bf16x8 af[4], bfm[4];
#pragma unroll
        for (int x = 0; x < 4; x++) {
            af[x]  = *(const bf16x8*)(&As[wm * 64 + x * 16 + l16][quad * 8]);
            bfm[x] = *(const bf16x8*)(&Bs[wn * 64 + x * 16 + l16][quad * 8]);
        }
#pragma unroll
        for (int mi = 0; mi < 4; mi++)
#pragma unroll
            for (int ni = 0; ni < 4; ni++)
                acc[mi][ni] = __builtin_amdgcn_mfma_f32_16x16x32_bf16(af[mi], bfm[ni], acc[mi][ni], 0, 0, 0);
    }
#pragma unroll
    for (int ni = 0; ni < 4; ni++) {
        int col = n0 + wn * 64 + ni * 16 + l16;
        if (col < N) {
            float bv = 0.f;
            if (bias1) bv += bias1[col];
            if (bias2) bv += bias2[col];
#pragma unroll
            for (int mi = 0; mi < 4; mi++) {
                int r0 = m0 + wm * 64 + mi * 16 + quad * 4;
#pragma unroll
                for (int r = 0; r < 4; r++) {
                    float v = acc[mi][ni][r] + bv;
                    if (Cb) Cb[(size_t)(r0 + r) * ldc + col] = f2bf(v);
                    else    Cf[(size_t)(r0 + r) * ldc + col] = v;
                }
            }
        }
    }
}

// ---------------------------------------------------------------------------
// Shared-memory union. R19: Wk/Wv/Wm2 are REGISTER-cached per lane (the
// sweep is LDS-issue-pipe-bound: R16's 2-blk/CU null + R17's batching null
// both point at the per-CU LDS pipe; cut LDS instr count, not order).
// SmemSlot drops WkT/WvT/Wm2T.
// ---------------------------------------------------------------------------
struct SmemLstm {
    u16 Wx[32][528];
    u16 Wh[32][528];
    float zs[4][16][33];
};
struct SmemSlot {
    float WqT[32][33], Wm1T[32][65], WspT[64][33];
    float bq[32], bk[32], bv[32], bm1[64], bm2[32], bsp[32], g[32], be[32];
    u16 xbuf[8][192];
    float slots[8][3][32], initl[8][3][32], kk[8][3][32], vv[8][3][32], qq[8][3][32];
    float att[8][3][4];
    float ubuf[8][32];
    float hid[8][64];
};
struct SmemScan {
    float r1s[32], r2s[32], fis[32], u1s[32], u2s[32];
    float red[8][32];
    float wred[4];
    float gpart[4];
};
union SmemU {
    SmemLstm l;
    SmemSlot s;
    SmemScan c;
};

__device__ __forceinline__ void stage_slot_weights(SmemSlot& S, const int tid,
    const float* __restrict__ Wq, const float* __restrict__ bq,
    const float* __restrict__ bk, const float* __restrict__ bv,
    const float* __restrict__ lng, const float* __restrict__ lnb,
    const float* __restrict__ Wm1, const float* __restrict__ bm1,
    const float* __restrict__ bm2,
    const float* __restrict__ Wsp, const float* __restrict__ bsp)
{
    for (int i = tid; i < 1024; i += 256) { int o = i >> 5, c = i & 31; S.WqT[c][o] = Wq[o * 32 + c]; }
    for (int i = tid; i < 2048; i += 256) {
        int o6 = i >> 6, c6 = i & 63;
        S.WspT[c6][o6] = Wsp[o6 * 64 + c6];
        int o5 = i >> 5, c5 = i & 31;
        S.Wm1T[c5][o5] = Wm1[o5 * 32 + c5];
    }
    if (tid < 32) {
        S.bq[tid] = bq[tid]; S.bk[tid] = bk[tid]; S.bv[tid] = bv[tid];
        S.bm2[tid] = bm2[tid]; S.bsp[tid] = bsp[tid];
        S.g[tid] = lng[tid]; S.be[tid] = lnb[tid];
    }
    if (tid < 64) S.bm1[tid] = bm1[tid];
}

// Register-cached weight columns for lane l: wk[c]=Wk[l*64+c], wv, wm2.
// Contiguous rows -> float4 global loads; indices constant after unroll ->
// promoted to VGPRs (~192 extra; <512 budget at 1 blk/CU, no occupancy loss).
template <int NSLOT>
__device__ __forceinline__ void slot_unit(
    SmemSlot& S, const int tid, const size_t row0,
    const u16* __restrict__ dec, const u16* __restrict__ initp,
    const float* __restrict__ wk, const float* __restrict__ wv,
    const float* __restrict__ wm2,
    float* __restrict__ o1, float* __restrict__ o2, float* __restrict__ o3)
{
    const int p = tid >> 5, l = tid & 31;
    const size_t row = row0 + p;
    for (int i = l; i < 192; i += 32) S.xbuf[p][i] = dec[row * 192 + i];
    wb();
    // k/v projection: reg weights, one u64 LDS read per 4 bf16 inputs
#pragma unroll
    for (int i = 0; i < 3; i++) {
        float k0 = 0.f, k1 = 0.f, v0 = 0.f, v1 = 0.f;
#pragma unroll
        for (int c = 0; c < 64; c += 4) {
            u64 xw = *(const u64*)(&S.xbuf[p][i * 64 + c]);
            float x0 = bf2f((u16)xw);
            float x1 = bf2f((u16)(xw >> 16));
            float x2 = bf2f((u16)(xw >> 32));
            float x3 = bf2f((u16)(xw >> 48));
            k0 += x0 * wk[c];     k1 += x1 * wk[c + 1];
            k0 += x2 * wk[c + 2]; k1 += x3 * wk[c + 3];
            v0 += x0 * wv[c];     v1 += x1 * wv[c + 1];
            v0 += x2 * wv[c + 2]; v1 += x3 * wv[c + 3];
        }
        S.kk[p][i][l] = elu1(S.bk[l] + (k0 + k1));
        S.vv[p][i][l] = S.bv[l] + (v0 + v1);
    }
#pragma unroll
    for (int j = 0; j < NSLOT; j++) {
        float iv = bf2f(initp[row * (NSLOT * 32) + j * 32 + l]);
        S.initl[p][j][l] = iv;
        S.slots[p][j][l] = iv;
    }
    wb();
    const float rs = 0.17677669529663687f;
    for (int it = 0; it < 3; it++) {
#pragma unroll
        for (int j = 0; j < NSLOT; j++) {
            float a0 = 0.f, a1 = 0.f, a2 = 0.f, a3 = 0.f;
#pragma unroll
            for (int c = 0; c < 32; c += 4) {
                f32x4 sv = *(const f32x4*)(&S.slots[p][j][c]);
                a0 += sv[0] * S.WqT[c][l];     a1 += sv[1] * S.WqT[c + 1][l];
                a2 += sv[2] * S.WqT[c + 2][l]; a3 += sv[3] * S.WqT[c + 3][l];
            }
            S.qq[p][j][l] = elu1((S.bq[l] + ((a0 + a1) + (a2 + a3)) + S.initl[p][j][l]) * rs);
        }
        wb();
        if (l < 3 * NSLOT) {
            int i = l / NSLOT, j = l % NSLOT;
            float a0 = 0.f, a1 = 0.f, a2 = 0.f, a3 = 0.f;
#pragma unroll
            for (int c = 0; c < 32; c += 4) {
                f32x4 kv = *(const f32x4*)(&S.kk[p][i][c]);
                f32x4 qv = *(const f32x4*)(&S.qq[p][j][c]);
                a0 += kv[0] * qv[0]; a1 += kv[1] * qv[1];
                a2 += kv[2] * qv[2]; a3 += kv[3] * qv[3];
            }
            S.att[p][i][j] = (a0 + a1) + (a2 + a3);
        }
        wb();
        if (l < 3) {
            float mx = -1e30f;
            for (int j = 0; j < NSLOT; j++) mx = fmaxf(mx, S.att[p][l][j]);
            float sm = 0.f, ex[3];
            for (int j = 0; j < NSLOT; j++) { ex[j] = __expf(S.att[p][l][j] - mx); sm += ex[j]; }
            for (int j = 0; j < NSLOT; j++) S.att[p][l][j] = ex[j] / sm + 1e-8f;
        }
        wb();
        if (l < NSLOT) {
            float s = S.att[p][0][l] + S.att[p][1][l] + S.att[p][2][l];
            float inv = 1.0f / s;
            for (int i = 0; i < 3; i++) S.att[p][i][l] *= inv;
        }
        wb();
#pragma unroll
        for (int j = 0; j < NSLOT; j++) {
            float u = S.att[p][0][j] * S.vv[p][0][l] + S.att[p][1][j] * S.vv[p][1][l] + S.att[p][2][j] * S.vv[p][2][l];
            float mean = u;
            for (int mk = 1; mk < 32; mk <<= 1) mean += __shfl_xor(mean, mk, 32);
            mean *= (1.0f / 32.0f);
            float d = u - mean;
            float var = d * d;
            for (int mk = 1; mk < 32; mk <<= 1) var += __shfl_xor(var, mk, 32);
            var *= (1.0f / 32.0f);
            float y = d * rsqrtf(var + 1e-5f) * S.g[l] + S.be[l];
            S.ubuf[p][l] = y;
            wb();
#pragma unroll
            for (int oo = 0; oo < 2; oo++) {
                int o = l + oo * 32;
                float a0 = 0.f, a1 = 0.f, a2 = 0.f, a3 = 0.f;
#pragma unroll
                for (int c = 0; c < 32; c += 4) {
                    f32x4 uv = *(const f32x4*)(&S.ubuf[p][c]);
                    a0 += uv[0] * S.Wm1T[c][o];     a1 += uv[1] * S.Wm1T[c + 1][o];
                    a2 += uv[2] * S.Wm1T[c + 2][o]; a3 += uv[3] * S.Wm1T[c + 3][o];
                }
                S.hid[p][o] = fmaxf(S.bm1[o] + ((a0 + a1) + (a2 + a3)), 0.f);
            }
            wb();
            float a0 = 0.f, a1 = 0.f, a2 = 0.f, a3 = 0.f;
#pragma unroll
            for (int c = 0; c < 64; c += 4) {
                f32x4 hv = *(const f32x4*)(&S.hid[p][c]);
                a0 += hv[0] * wm2[c];     a1 += hv[1] * wm2[c + 1];
                a2 += hv[2] * wm2[c + 2]; a3 += hv[3] * wm2[c + 3];
            }
            S.slots[p][j][l] += (S.bm2[l] + ((a0 + a1) + (a2 + a3))) * (1.0f / 32.0f);
            wb();
        }
    }
    float pj[NSLOT];
#pragma unroll
    for (int j = 0; j < NSLOT; j++) {
        float a0 = 0.f, a1 = 0.f, a2 = 0.f, a3 = 0.f;
#pragma unroll
        for (int c = 0; c < 32; c += 4) {
            f32x4 iv = *(const f32x4*)(&S.initl[p][j][c]);
            a0 += iv[0] * S.WspT[c][l];     a1 += iv[1] * S.WspT[c + 1][l];
            a2 += iv[2] * S.WspT[c + 2][l]; a3 += iv[3] * S.WspT[c + 3][l];
        }
#pragma unroll
        for (int c = 0; c < 32; c += 4) {
            f32x4 sv = *(const f32x4*)(&S.slots[p][j][c]);
            a0 += sv[0] * S.WspT[32 + c][l];     a1 += sv[1] * S.WspT[32 + c + 1][l];
            a2 += sv[2] * S.WspT[32 + c + 2][l]; a3 += sv[3] * S.WspT[32 + c + 3][l];
        }
        pj[j] = S.bsp[l] + ((a0 + a1) + (a2 + a3));
    }
    const float e = 1e-6f, me = (float)(1.0 - 2e-6);
    if (NSLOT == 3) {
        ag_storef(&o1[row * 32 + l], tanhf(me * pj[0] + e * pj[1] + e * pj[2]));
        ag_storef(&o2[row * 32 + l], tanhf(e * pj[0] + me * pj[1] + e * pj[2]));
        ag_storef(&o3[row * 32 + l], tanhf(e * pj[0] + e * pj[1] + me * pj[2]));
    } else {
        ag_storef(&o1[row * 32 + l], tanhf(me * pj[0] + e * pj[1]));
        ag_storef(&o2[row * 32 + l], tanhf(e * pj[0] + me * pj[1]));
    }
}

// ---------------------------------------------------------------------------
// Mega kernel, 256 blocks (exactly 1/CU):
//   0..127   LSTM (R10 champion verbatim)
//   128..191 scan (dual gate: f1s + worker progress)
//   192..255 64 slot workers (R13 protocol), all 8192 units (u%64),
//            reg-cached weights (R19).
// X=0 family member (R13 = 3276 was its best); reg-caching targets the
// 24.5us/unit LDS-pipe bound. Downside bounded at ~R13 perf.
//   flags: f0 @0, f1 @4096, f1s @8192, prog @12288 (64 x stride-16)
// ---------------------------------------------------------------------------
__global__ __launch_bounds__(256) void k_mega(
    const u16* __restrict__ emb,
    const u16* __restrict__ Wx0, const u16* __restrict__ Wh0,
    const u16* __restrict__ Wx1, const u16* __restrict__ Wh1,
    const float* __restrict__ bi0, const float* __restrict__ bh0,
    const float* __restrict__ bi1, const float* __restrict__ bh1,
    u16* __restrict__ h0seq,        // [512][64][64][8] block-major
    u16* __restrict__ h1seq,        // [512][64][64][8] block-major
    u16* __restrict__ acat,         // [32768][544]; cols 0..511 h1, 512.. scan out
    int* __restrict__ flags,
    float* __restrict__ r1, float* __restrict__ r2,
    float* __restrict__ fi, float* __restrict__ uu1, float* __restrict__ uu2,
    const float* __restrict__ Wg, const float* __restrict__ bg,
    const u16* __restrict__ dec,
    const u16* __restrict__ initb, const u16* __restrict__ initr,
    const float* __restrict__ Wq, const float* __restrict__ bq,
    const float* __restrict__ Wk, const float* __restrict__ bk,
    const float* __restrict__ Wv, const float* __restrict__ bv,
    const float* __restrict__ lng, const float* __restrict__ lnb,
    const float* __restrict__ Wm1, const float* __restrict__ bm1,
    const float* __restrict__ Wm2, const float* __restrict__ bm2,
    const float* __restrict__ Wsp, const float* __restrict__ bsp)
{
    __shared__ SmemU sm;
    const int tid = threadIdx.x;
    const int blk = blockIdx.x;
    int* f0   = flags;
    int* f1   = flags + 4096;
    int* f1s  = flags + 8192;
    int* prog = flags + 12288;

    if (blk < 128) {
        // =================== wave-autonomous LSTM (R10 verbatim) ==========
        auto& Wx = sm.l.Wx;
        auto& Wh = sm.l.Wh;
        auto& zs = sm.l.zs;
        const int layer = blk >> 6;
        const int me = blk & 63;
        const int jbase = me * 8;
        const int Kx = layer ? 512 : 256;
        const u16* Wxp = layer ? Wx1 : Wx0;
        const u16* Whp = layer ? Wh1 : Wh0;
        const float* bi = layer ? bi1 : bi0;
        const float* bh = layer ? bh1 : bh0;
#pragma unroll
        for (int i = 0; i < 8; i++) {
            int c = tid + i * 256;
            int row = c >> 6, cc = (c & 63) * 8;
            int grow = (row >> 3) * 512 + jbase + (row & 7);
            *(uint4*)(&Wh[row][cc]) = *(const uint4*)(Whp + (size_t)grow * 512 + cc);
        }
        {
            int cpr = Kx >> 3;
            int iters = (32 * cpr) >> 8;
            for (int i = 0; i < iters; i++) {
                int c = tid + i * 256;
                int row = c / cpr, cc = (c % cpr) * 8;
                int grow = (row >> 3) * 512 + jbase + (row & 7);
                *(uint4*)(&Wx[row][cc]) = *(const uint4*)(Wxp + (size_t)grow * Kx + cc);
            }
        }
        const int wave = tid >> 6, lane = tid & 63;
        const int quad = lane >> 4, l16 = lane & 15;
        const int m = wave * 16 + l16;
        const int bl = lane >> 2;
        const int b = wave * 16 + bl;
        const int jj = (lane & 3) * 2;
        const int hoff = quad * 512 + m * 8;
        float bia0[4], bia1[4];
#pragma unroll
        for (int g = 0; g < 4; g++) {
            bia0[g] = bi[g * 512 + jbase + jj]     + bh[g * 512 + jbase + jj];
            bia1[g] = bi[g * 512 + jbase + jj + 1] + bh[g * 512 + jbase + jj + 1];
        }
        const int pollOwn = (wave * 64 + lane) * 16;
        const int pubIdx  = (wave * 64 + me) * 16;
        float c0 = 0.f, c1 = 0.f;
        __syncthreads();
        for (int t = 0; t < 512; t++) {
            f32x4 acc0 = {}, acc1 = {};
            if (!layer) {
                const u16* xrow = emb + ((size_t)t * 64 + m) * 256;
#pragma unroll
                for (int kc = 0; kc < 8; kc++) {
                    bf16x8 a  = *(const bf16x8*)(xrow + kc * 32 + quad * 8);
                    bf16x8 w0 = *(const bf16x8*)(&Wx[l16][kc * 32 + quad * 8]);
                    bf16x8 w1 = *(const bf16x8*)(&Wx[16 + l16][kc * 32 + quad * 8]);
                    acc0 = __builtin_amdgcn_mfma_f32_16x16x32_bf16(a, w0, acc0, 0, 0, 0);
                    acc1 = __builtin_amdgcn_mfma_f32_16x16x32_bf16(a, w1, acc1, 0, 0, 0);
                }
                if (t > 0) {
                    int it = 0;
                    for (;;) {
                        int a = ag_load(f0 + pollOwn);
                        if (__all(a >= t)) break;
                        if (++it > 3000000) break;
                        __builtin_amdgcn_s_sleep(1);
                    }
                    const u16* hrd = h0seq + (size_t)(t - 1) * 32768 + hoff;
#pragma unroll
                    for (int kc = 0; kc < 16; kc++) {
                        bf16x8 a  = *(const bf16x8*)(hrd + kc * 2048);
                        bf16x8 w0 = *(const bf16x8*)(&Wh[l16][kc * 32 + quad * 8]);
                        bf16x8 w1 = *(const bf16x8*)(&Wh[16 + l16][kc * 32 + quad * 8]);
                        acc0 = __builtin_amdgcn_mfma_f32_16x16x32_bf16(a, w0, acc0, 0, 0, 0);
                        acc1 = __builtin_amdgcn_mfma_f32_16x16x32_bf16(a, w1, acc1, 0, 0, 0);
                    }
                }
            } else {
                {
                    int it = 0;
                    for (;;) {
                        int a = ag_load(f0 + pollOwn);
                        if (__all(a >= t + 1)) break;
                        if (++it > 3000000) break;
                        __builtin_amdgcn_s_sleep(1);
                    }
                }
                const u16* xrow = h0seq + (size_t)t * 32768 + hoff;
#pragma unroll
                for (int kc = 0; kc < 16; kc++) {
                    bf16x8 a  = *(const bf16x8*)(xrow + kc * 2048);
                    bf16x8 w0 = *(const bf16x8*)(&Wx[l16][kc * 32 + quad * 8]);
                    bf16x8 w1 = *(const bf16x8*)(&Wx[16 + l16][kc * 32 + quad * 8]);
                    acc0 = __builtin_amdgcn_mfma_f32_16x16x32_bf16(a, w0, acc0, 0, 0, 0);
                    acc1 = __builtin_amdgcn_mfma_f32_16x16x32_bf16(a, w1, acc1, 0, 0, 0);
                }
                if (t > 0) {
                    int it = 0;
                    for (;;) {
                        int a = ag_load(f1 + pollOwn);
                        if (__all(a >= t)) break;
                        if (++it > 3000000) break;
                        __builtin_amdgcn_s_sleep(1);
                    }
                    const u16* hrd = h1seq + (size_t)(t - 1) * 32768 + hoff;
#pragma unroll
                    for (int kc = 0; kc < 16; kc++) {
                        bf16x8 a  = *(const bf16x8*)(hrd + kc * 2048);
                        bf16x8 w0 = *(const bf16x8*)(&Wh[l16][kc * 32 + quad * 8]);
                        bf16x8 w1 = *(const bf16x8*)(&Wh[16 + l16][kc * 32 + quad * 8]);
                        acc0 = __builtin_amdgcn_mfma_f32_16x16x32_bf16(a, w0, acc0, 0, 0, 0);
                        acc1 = __builtin_amdgcn_mfma_f32_16x16x32_bf16(a, w1, acc1, 0, 0, 0);
                    }
                }
            }
#pragma unroll
            for (int r = 0; r < 4; r++) {
                zs[wave][quad * 4 + r][l16]      = acc0[r];
                zs[wave][quad * 4 + r][16 + l16] = acc1[r];
            }
            u16 hb0, hb1;
            {
                float zi0 = zs[wave][bl][jj]      + bia0[0];
                float zf0 = zs[wave][bl][8 + jj]  + bia0[1];
                float zg0 = zs[wave][bl][16 + jj] + bia0[2];
                float zo0 = zs[wave][bl][24 + jj] + bia0[3];
                c0 = sigm(zf0) * c0 + sigm(zi0) * tanhf(zg0);
                float h0v = sigm(zo0) * tanhf(c0);
                float zi1 = zs[wave][bl][jj + 1]      + bia1[0];
                float zf1 = zs[wave][bl][8 + jj + 1]  + bia1[1];
                float zg1 = zs[wave][bl][16 + jj + 1] + bia1[2];
                float zo1 = zs[wave][bl][24 + jj + 1] + bia1[3];
                c1 = sigm(zf1) * c1 + sigm(zi1) * tanhf(zg1);
                float h1v = sigm(zo1) * tanhf(c1);
                hb0 = f2bf(h0v); hb1 = f2bf(h1v);
            }
            if (!layer) {
                llc_store2(h0seq + (size_t)t * 32768 + me * 512 + b * 8 + jj, hb0, hb1);
                __builtin_amdgcn_s_waitcnt(0);
                if (lane == 0) ag_store(f0 + pubIdx, t + 1);
            } else {
                llc_store2(h1seq + (size_t)t * 32768 + me * 512 + b * 8 + jj, hb0, hb1);
                __builtin_amdgcn_s_waitcnt(0);
                if (lane == 0) ag_store(f1 + pubIdx, t + 1);
                llc_store2(acat + ((size_t)t * 64 + b) * 544 + jbase + jj, hb0, hb1);
                __builtin_amdgcn_s_waitcnt(0);
                if (lane == 0) ag_store(f1s + pubIdx, t + 1);
            }
        }
    } else if (blk < 192) {
        // =================== trailing scan + inline gate ==================
        const int sb = blk - 128;
        const int grp = sb >> 4;
        const int f = tid & 31, rg = tid >> 5;
        float m[4][32];
#pragma unroll
        for (int x = 0; x < 4; x++)
            for (int y = 0; y < 32; y++) m[x][y] = 0.f;
        auto& r1s = sm.c.r1s;
        auto& r2s = sm.c.r2s;
        auto& fis = sm.c.fis;
        auto& u1s = sm.c.u1s;
        auto& u2s = sm.c.u2s;
        auto& red = sm.c.red;
        auto& wred = sm.c.wred;
        auto& gpart = sm.c.gpart;
        float wg0 = Wg[2 * tid], wg1 = Wg[2 * tid + 1];
        float bgv = bg[0];
        for (int t = 0; t < 512; t++) {
            // dual gate: wave0 polls LSTM f1s; wave1 polls worker progress
            if (tid < 64) {
                int* p1 = f1s + (grp * 64 + tid) * 16;
                int it = 0;
                for (;;) {
                    int a = ag_load(p1);
                    if (__all(a >= t + 1)) break;
                    if (++it > 3000000) break;
                    __builtin_amdgcn_s_sleep(1);
                }
            } else if (tid < 128) {
                const int k = tid - 64;
                const int* pp = prog + k * 16;
                const int need = (t + 1) * 16;
                int it = 0;
                for (;;) {
                    int a = ag_load(pp);
                    if (__all(a >= need)) break;
                    if (++it > 3000000) break;
                    __builtin_amdgcn_s_sleep(1);
                }
            }
            __syncthreads();
            // preloads AFTER the gates (R13-validated ordering)
            float pre = 0.f;
            {
                size_t base = ((size_t)t * 64 + sb) * 32;
                if (tid < 32) pre = r1[base + tid];
                else if (tid < 64) pre = r2[base + tid - 32];
                else if (tid < 96) pre = fi[base + tid - 64];
                else if (tid < 128) pre = uu1[base + tid - 96];
                else if (tid < 160) pre = uu2[base + tid - 128];
            }
            {
                const u16* hr = acat + ((size_t)t * 64 + sb) * 544;
                u32 hv = *(const u32*)(hr + 2 * tid);
                float gp = bf2f((u16)hv) * wg0 + bf2f((u16)(hv >> 16)) * wg1;
                for (int mk = 1; mk < 64; mk <<= 1) gp += __shfl_xor(gp, mk, 64);
                if ((tid & 63) == 0) gpart[tid >> 6] = gp;
            }
            if (tid < 32) r1s[tid] = pre;
            else if (tid < 64) r2s[tid - 32] = pre;
            else if (tid < 96) fis[tid - 64] = pre;
            else if (tid < 128) u1s[tid - 96] = pre;
            else if (tid < 160) u2s[tid - 128] = pre;
            __syncthreads();
            float gsh = sigm(gpart[0] + gpart[1] + gpart[2] + gpart[3] + bgv + 1.0f);
            float p = 0.f;
#pragma unroll
            for (int rl = 0; rl < 4; rl++) {
                float s = 0.f;
                for (int ti = 0; ti < 32; ti++) s += r2s[ti] * m[rl][ti];
                p += r1s[rg * 4 + rl] * s;
            }
            red[rg][f] = p;
            __syncthreads();
            float prev = 0.f;
#pragma unroll
            for (int g = 0; g < 8; g++) prev += red[g][f];
            float curo = gsh * (fis[f] - prev) * (1.0f / 32.0f);
            float nsq = 0.f;
#pragma unroll
            for (int rl = 0; rl < 4; rl++) {
                float a = r1s[rg * 4 + rl] * curo;
                for (int ti = 0; ti < 32; ti++) {
                    m[rl][ti] += a * r2s[ti];
                    nsq += m[rl][ti] * m[rl][ti];
                }
            }
            for (int mk = 1; mk < 64; mk <<= 1) nsq += __shfl_xor(nsq, mk, 64);
            __syncthreads();
            if ((tid & 63) == 0) wred[tid >> 6] = nsq;
            __syncthreads();
            float nrm = sqrtf(wred[0] + wred[1] + wred[2] + wred[3]);
            float sc = nrm > 1.0f ? 1.0f / nrm : 1.0f;
            float rp = 0.f;
#pragma unroll
            for (int rl = 0; rl < 4; rl++) {
                float s = 0.f;
                for (int ti = 0; ti < 32; ti++) {
                    m[rl][ti] *= sc;
                    s += m[rl][ti] * u2s[ti];
                }
                rp += u1s[rg * 4 + rl] * s;
            }
            red[rg][f] = rp;
            __syncthreads();
            float rv = 0.f;
#pragma unroll
            for (int g = 0; g < 8; g++) rv += red[g][f];
            float mean = rv;
            for (int mk = 1; mk < 32; mk <<= 1) mean += __shfl_xor(mean, mk, 32);
            mean *= (1.0f / 32.0f);
            float d = rv - mean;
            float var = d * d;
            for (int mk = 1; mk < 32; mk <<= 1) var += __shfl_xor(var, mk, 32);
            var *= (1.0f / 32.0f);
            if (tid < 32) {
                float y = d * rsqrtf(var + 1e-5f);
                llc_store_u16(acat + ((size_t)t * 64 + sb) * 544 + 512 + f, f2bf(y));
            }
            __syncthreads();
        }
    } else {
        // =================== slot workers (blk 192..255, own CUs) =========
        const int wid = blk - 192;   // 0..63
        stage_slot_weights(sm.s, tid, Wq, bq, bk, bv, lng, lnb,
                           Wm1, bm1, bm2, Wsp, bsp);
        // register-cache lane-owned weight columns (rows of Wk/Wv/Wm2)
        const int l = tid & 31;
        float wk[64], wv[64], wm2c[64];
#pragma unroll
        for (int c = 0; c < 64; c += 4) {
            *(float4*)&wk[c]   = *(const float4*)(Wk  + l * 64 + c);
            *(float4*)&wv[c]   = *(const float4*)(Wv  + l * 64 + c);
            *(float4*)&wm2c[c] = *(const float4*)(Wm2 + l * 64 + c);
        }
        __syncthreads();
        int* myprog = prog + wid * 16;
        for (int u = wid; u < 8192; u += 64) {
            const int t = u >> 4, s = u & 15;
            if (s < 8)
                slot_unit<3>(sm.s, tid, (size_t)t * 64 + s * 8, dec, initb,
                             wk, wv, wm2c, r1, r2, fi);
            else
                slot_unit<2>(sm.s, tid, (size_t)t * 64 + (s - 8) * 8, dec, initr,
                             wk, wv, wm2c, uu1, uu2, nullptr);
            __builtin_amdgcn_s_waitcnt(0);   // output stores acked at LLC
            __syncthreads();                 // LDS reusable
            if (tid == 0) ag_store(myprog, u + 64);   // no pending unit < u+64
        }
    }
}

// ---------------------------------------------------------------------------
extern "C" void kernel_launch(void* const* d_in, const int* in_sizes, int n_in,
                              void* d_out, int out_size, void* d_ws, size_t ws_size,
                              hipStream_t stream)
{
    (void)in_sizes; (void)n_in; (void)out_size; (void)ws_size;
    const int*   tokens = (const int*)d_in[0];
    const float* embW  = (const float*)d_in[1];
    const float* Wih0  = (const float*)d_in[2];
    const float* Whh0  = (const float*)d_in[3];
    const float* bih0  = (const float*)d_in[4];
    const float* bhh0  = (const float*)d_in[5];
    const float* Wih1  = (const float*)d_in[6];
    const float* Whh1  = (const float*)d_in[7];
    const float* bih1  = (const float*)d_in[8];
    const float* bhh1  = (const float*)d_in[9];
    const float* Wpi   = (const float*)d_in[10];
    const float* bpi   = (const float*)d_in[11];
    const float* Wq    = (const float*)d_in[12];
    const float* bq    = (const float*)d_in[13];
    const float* Wk    = (const float*)d_in[14];
    const float* bk    = (const float*)d_in[15];
    const float* Wv    = (const float*)d_in[16];
    const float* bv    = (const float*)d_in[17];
    const float* lng   = (const float*)d_in[18];
    const float* lnb   = (const float*)d_in[19];
    const float* Wm1   = (const float*)d_in[20];
    const float* bm1   = (const float*)d_in[21];
    const float* Wm2   = (const float*)d_in[22];
    const float* bm2   = (const float*)d_in[23];
    const float* Wbind = (const float*)d_in[24];
    const float* bbind = (const float*)d_in[25];
    const float* Wreas = (const float*)d_in[26];
    const float* breas = (const float*)d_in[27];
    const float* Wsp   = (const float*)d_in[28];
    const float* bsp   = (const float*)d_in[29];
    const float* Wg    = (const float*)d_in[30];
    const float* bg    = (const float*)d_in[31];
    const float* Wout  = (const float*)d_in[32];
    const float* bout  = (const float*)d_in[33];

    char* ws = (char*)d_ws;
    size_t off = 0;
    auto alloc = [&](size_t bytes) { size_t o = off; off += (bytes + 255) & ~(size_t)255; return o; };
    int*  flags  = (int*)(ws + alloc(16384 * 4));   // f0, f1, f1s, prog
    u16*  emb    = (u16*)(ws + alloc(32768ull * 256 * 2));
    u16*  dec    = (u16*)(ws + alloc(32768ull * 192 * 2));
    u16*  initb  = (u16*)(ws + alloc(32768ull * 96 * 2));
    u16*  initr  = (u16*)(ws + alloc(32768ull * 64 * 2));
    u16*  acat   = (u16*)(ws + alloc(32768ull * 544 * 2));
    u16*  h0seq  = (u16*)(ws + alloc(512ull * 64 * 512 * 2));
    u16*  h1seq  = (u16*)(ws + alloc(512ull * 64 * 512 * 2));
    float* role1 = (float*)(ws + alloc(32768ull * 32 * 4));
    float* role2 = (float*)(ws + alloc(32768ull * 32 * 4));
    float* fill  = (float*)(ws + alloc(32768ull * 32 * 4));
    float* u1v   = (float*)(ws + alloc(32768ull * 32 * 4));
    float* u2v   = (float*)(ws + alloc(32768ull * 32 * 4));
    u16* Wx0b  = (u16*)(ws + alloc(2048ull * 256 * 2));
    u16* Wh0b  = (u16*)(ws + alloc(2048ull * 512 * 2));
    u16* Wx1b  = (u16*)(ws + alloc(2048ull * 512 * 2));
    u16* Wh1b  = (u16*)(ws + alloc(2048ull * 512 * 2));
    u16* Wpib  = (u16*)(ws + alloc(192ull * 256 * 2));
    u16* Wbindb = (u16*)(ws + alloc(96ull * 192 * 2));
    u16* Wreasb = (u16*)(ws + alloc(64ull * 192 * 2));
    u16* Woutb  = (u16*)(ws + alloc(128ull * 544 * 2));

    hipMemsetAsync(flags, 0, 16384 * 4, stream);
    {
        Cvt8 c;
        const float* s[8] = {Wih0, Whh0, Wih1, Whh1, Wpi, Wbind, Wreas, Wout};
        u16* d[8] = {Wx0b, Wh0b, Wx1b, Wh1b, Wpib, Wbindb, Wreasb, Woutb};
        int n[8] = {2048 * 256, 2048 * 512, 2048 * 512, 2048 * 512,
                    192 * 256, 96 * 192, 64 * 192, 128 * 544};
        int acc = 0;
        for (int k = 0; k < 8; k++) { c.s[k] = s[k]; c.d[k] = d[k]; c.off4[k] = acc; acc += n[k] / 4; }
        c.off4[8] = acc;
        k_f2b8<<<(acc + 255) / 256, 256, 0, stream>>>(c);
    }
    k_embed<<<4096, 256, 0, stream>>>(tokens, embW, emb);
    k_gemm_bt<<<dim3(256, 2), 256, 0, stream>>>(emb, 256, Wpib, dec, nullptr, 192, bpi, nullptr, 192, 256);
    k_gemm_bt<<<dim3(256, 1), 256, 0, stream>>>(dec, 192, Wbindb, initb, nullptr, 96, bbind, nullptr, 96, 192);
    k_gemm_bt<<<dim3(256, 1), 256, 0, stream>>>(dec, 192, Wreasb, initr, nullptr, 64, breas, nullptr, 64, 192);
    // fused: LSTM + scan + 64 reg-cached slot workers (1 block/CU)
    k_mega<<<256, 256, 0, stream>>>(emb, Wx0b, Wh0b, Wx1b, Wh1b,
                                    bih0, bhh0, bih1, bhh1,
                                    h0seq, h1seq, acat, flags,
                                    role1, role2, fill, u1v, u2v, Wg, bg,
                                    dec, initb, initr,
                                    Wq, bq, Wk, bk, Wv, bv, lng, lnb,
                                    Wm1, bm1, Wm2, bm2, Wsp, bsp);
    // out = acat @ Wout^T + bout  (fp32 output)
    k_gemm_bt<<<dim3(256, 1), 256, 0, stream>>>(acat, 544, Woutb, nullptr, (float*)d_out, 128, bout, nullptr, 128, 544);
}

// Round 13
// 4006.436 us; speedup vs baseline: 1.2505x; 1.2505x over previous
//
#include <hip/hip_runtime.h>

typedef unsigned short u16;
typedef unsigned int u32;
typedef unsigned long long u64;
typedef __bf16 bf16x8 __attribute__((ext_vector_type(8)));
typedef float f32x4 __attribute__((ext_vector_type(4)));

__device__ __forceinline__ float bf2f(u16 u) { return __uint_as_float(((u32)u) << 16); }
__device__ __forceinline__ u16 f2bf(float f) {
    u32 u = __float_as_uint(f);
    u32 r = (u + 0x7FFFu + ((u >> 16) & 1u)) >> 16;
    return (u16)r;
}
__device__ __forceinline__ float sigm(float x) { return 1.0f / (1.0f + __expf(-x)); }
__device__ __forceinline__ float elu1(float x) { return x > 0.0f ? x + 1.0f : __expf(x); }

// Zero-cost intra-wave phase fence (R16-validated)
__device__ __forceinline__ void wb() { __builtin_amdgcn_wave_barrier(); }

// agent-scope (LLC) atomics — HW-validated cross-XCD path (R5/R7/R13)
__device__ __forceinline__ int ag_load(const int* p) {
    return __hip_atomic_load(p, __ATOMIC_RELAXED, __HIP_MEMORY_SCOPE_AGENT);
}
__device__ __forceinline__ void ag_store(int* p, int v) {
    __hip_atomic_store(p, v, __ATOMIC_RELAXED, __HIP_MEMORY_SCOPE_AGENT);
}
__device__ __forceinline__ void ag_storef(float* p, float v) {
    __hip_atomic_store(p, v, __ATOMIC_RELAXED, __HIP_MEMORY_SCOPE_AGENT);
}
__device__ __forceinline__ void llc_store2(u16* p, u16 a, u16 b) {
    u32 v = (u32)a | ((u32)b << 16);
    __hip_atomic_store((u32*)p, v, __ATOMIC_RELAXED, __HIP_MEMORY_SCOPE_AGENT);
}
__device__ __forceinline__ void llc_store_u16(u16* p, u16 v) {
    __hip_atomic_store(p, v, __ATOMIC_RELAXED, __HIP_MEMORY_SCOPE_AGENT);
}

// ---------------------------------------------------------------------------
struct Cvt8 { const float* s[8]; u16* d[8]; int off4[9]; };

__global__ __launch_bounds__(256) void k_f2b8(Cvt8 c)
{
    int i = blockIdx.x * 256 + threadIdx.x;
    if (i >= c.off4[8]) return;
    int k = 0;
#pragma unroll
    for (int q = 1; q < 8; q++) if (i >= c.off4[q]) k = q;
    int j = i - c.off4[k];
    float4 v = ((const float4*)c.s[k])[j];
    ushort4 o;
    o.x = f2bf(v.x); o.y = f2bf(v.y); o.z = f2bf(v.z); o.w = f2bf(v.w);
    ((ushort4*)c.d[k])[j] = o;
}

// ---------------------------------------------------------------------------
__global__ __launch_bounds__(256) void k_embed(const int* __restrict__ tok,
                                               const float* __restrict__ W,
                                               u16* __restrict__ out)
{
    int c = blockIdx.x * 256 + threadIdx.x;
    int row = c >> 5, cc = (c & 31) * 8;
    int t = tok[row];
    const float* src = W + (size_t)t * 256 + cc;
    u16 tmp[8];
#pragma unroll
    for (int k = 0; k < 8; k++) tmp[k] = f2bf(src[k]);
    *(uint4*)(out + (size_t)row * 256 + cc) = *(uint4*)tmp;
}

// ---------------------------------------------------------------------------
// GEMM:  C[M,N] = A[M,K](bf16, lda) * B[N,K]^T(bf16) + bias. 128x128 tile.
// ---------------------------------------------------------------------------
__global__ __launch_bounds__(256) void k_gemm_bt(
    const u16* __restrict__ A, int lda,
    const u16* __restrict__ B,
    u16* __restrict__ Cb, float* __restrict__ Cf, int ldc,
    const float* __restrict__ bias1, const float* __restrict__ bias2,
    int N, int K)
{
    __shared__ u16 As[128][40];
    __shared__ u16 Bs[128][40];
    const int tid = threadIdx.x;
    const int m0 = blockIdx.x * 128, n0 = blockIdx.y * 128;
    const int wave = tid >> 6, lane = tid & 63;
    const int wm = wave & 1, wn = wave >> 1;
    const int quad = lane >> 4, l16 = lane & 15;
    f32x4 acc[4][4] = {};
    for (int k0 = 0; k0 < K; k0 += 32) {
        __syncthreads();
#pragma unroll
        for (int i = 0; i < 2; i++) {
            int c = tid + i * 256, row = c >> 2, cc = (c & 3) * 8;
            *(uint4*)(&As[row][cc]) = *(const uint4*)(A + (size_t)(m0 + row) * lda + k0 + cc);
            uint4 d = {0, 0, 0, 0};
            if (n0 + row < N) d = *(const uint4*)(B + (size_t)(n0 + row) * K + k0 + cc);
            *(uint4*)(&Bs[row][cc]) = d;
        }
        __syncthreads();
        bf16x8 af[4], bfm[4];
#pragma unroll
        for (int x = 0; x < 4; x++) {
            af[x]  = *(const bf16x8*)(&As[wm * 64 + x * 16 + l16][quad * 8]);
            bfm[x] = *(const bf16x8*)(&Bs[wn * 64 + x * 16 + l16][quad * 8]);
        }
#pragma unroll
        for (int mi = 0; mi < 4; mi++)
#pragma unroll
            for (int ni = 0; ni < 4; ni++)
                acc[mi][ni] = __builtin_amdgcn_mfma_f32_16x16x32_bf16(af[mi], bfm[ni], acc[mi][ni], 0, 0, 0);
    }
#pragma unroll
    for (int ni = 0; ni < 4; ni++) {
        int col = n0 + wn * 64 + ni * 16 + l16;
        if (col < N) {
            float bv = 0.f;
            if (bias1) bv += bias1[col];
            if (bias2) bv += bias2[col];
#pragma unroll
            for (int mi = 0; mi < 4; mi++) {
                int r0 = m0 + wm * 64 + mi * 16 + quad * 4;
#pragma unroll
                for (int r = 0; r < 4; r++) {
                    float v = acc[mi][ni][r] + bv;
                    if (Cb) Cb[(size_t)(r0 + r) * ldc + col] = f2bf(v);
                    else    Cf[(size_t)(r0 + r) * ldc + col] = v;
                }
            }
        }
    }
}

// ---------------------------------------------------------------------------
// Shared-memory union (full LDS weight arrays — R19's reg cache spilled to
// scratch at VGPR 240 and doubled unit cost; reverted).
// ---------------------------------------------------------------------------
struct SmemLstm {
    u16 Wx[32][528];
    u16 Wh[32][528];
    float zs[4][16][33];
};
struct SmemSlot {
    float WqT[32][33], WkT[64][33], WvT[64][33], Wm1T[32][65], Wm2T[64][33], WspT[64][33];
    float bq[32], bk[32], bv[32], bm1[64], bm2[32], bsp[32], g[32], be[32];
    u16 xbuf[8][192];
    float slots[8][3][32], initl[8][3][32], kk[8][3][32], vv[8][3][32], qq[8][3][32];
    float att[8][3][4];
    float ubuf[8][32];
    float hid[8][64];
};
struct SmemScan {
    float r1s[32], r2s[32], fis[32], u1s[32], u2s[32];
    float red[8][32];
    float wred[4];
    float gpart[4];
};
union SmemU {
    SmemLstm l;
    SmemSlot s;
    SmemScan c;
};

__device__ __forceinline__ void stage_slot_weights(SmemSlot& S, const int tid,
    const float* __restrict__ Wq, const float* __restrict__ bq,
    const float* __restrict__ Wk, const float* __restrict__ bk,
    const float* __restrict__ Wv, const float* __restrict__ bv,
    const float* __restrict__ lng, const float* __restrict__ lnb,
    const float* __restrict__ Wm1, const float* __restrict__ bm1,
    const float* __restrict__ Wm2, const float* __restrict__ bm2,
    const float* __restrict__ Wsp, const float* __restrict__ bsp)
{
    for (int i = tid; i < 1024; i += 256) { int o = i >> 5, c = i & 31; S.WqT[c][o] = Wq[o * 32 + c]; }
    for (int i = tid; i < 2048; i += 256) {
        int o6 = i >> 6, c6 = i & 63;
        S.WkT[c6][o6]  = Wk[o6 * 64 + c6];
        S.WvT[c6][o6]  = Wv[o6 * 64 + c6];
        S.Wm2T[c6][o6] = Wm2[o6 * 64 + c6];
        S.WspT[c6][o6] = Wsp[o6 * 64 + c6];
        int o5 = i >> 5, c5 = i & 31;
        S.Wm1T[c5][o5] = Wm1[o5 * 32 + c5];
    }
    if (tid < 32) {
        S.bq[tid] = bq[tid]; S.bk[tid] = bk[tid]; S.bv[tid] = bv[tid];
        S.bm2[tid] = bm2[tid]; S.bsp[tid] = bsp[tid];
        S.g[tid] = lng[tid]; S.be[tid] = lnb[tid];
    }
    if (tid < 64) S.bm1[tid] = bm1[tid];
}

// R17-batched slot unit (validated R17/R18): 4-wide load batches + split
// accumulators; agent-scope output stores (in-mega workers).
template <int NSLOT>
__device__ __forceinline__ void slot_unit(
    SmemSlot& S, const int tid, const size_t row0,
    const u16* __restrict__ dec, const u16* __restrict__ initp,
    float* __restrict__ o1, float* __restrict__ o2, float* __restrict__ o3)
{
    const int p = tid >> 5, l = tid & 31;
    const size_t row = row0 + p;
    for (int i = l; i < 192; i += 32) S.xbuf[p][i] = dec[row * 192 + i];
    wb();
#pragma unroll
    for (int i = 0; i < 3; i++) {
        float k0 = 0.f, k1 = 0.f, v0 = 0.f, v1 = 0.f;
#pragma unroll
        for (int c = 0; c < 64; c += 4) {
            u64 xw = *(const u64*)(&S.xbuf[p][i * 64 + c]);
            float x0 = bf2f((u16)xw);
            float x1 = bf2f((u16)(xw >> 16));
            float x2 = bf2f((u16)(xw >> 32));
            float x3 = bf2f((u16)(xw >> 48));
            float wk0 = S.WkT[c][l], wk1 = S.WkT[c + 1][l];
            float wk2 = S.WkT[c + 2][l], wk3 = S.WkT[c + 3][l];
            float wv0 = S.WvT[c][l], wv1 = S.WvT[c + 1][l];
            float wv2 = S.WvT[c + 2][l], wv3 = S.WvT[c + 3][l];
            k0 += x0 * wk0; k1 += x1 * wk1; k0 += x2 * wk2; k1 += x3 * wk3;
            v0 += x0 * wv0; v1 += x1 * wv1; v0 += x2 * wv2; v1 += x3 * wv3;
        }
        S.kk[p][i][l] = elu1(S.bk[l] + (k0 + k1));
        S.vv[p][i][l] = S.bv[l] + (v0 + v1);
    }
#pragma unroll
    for (int j = 0; j < NSLOT; j++) {
        float iv = bf2f(initp[row * (NSLOT * 32) + j * 32 + l]);
        S.initl[p][j][l] = iv;
        S.slots[p][j][l] = iv;
    }
    wb();
    const float rs = 0.17677669529663687f;
    for (int it = 0; it < 3; it++) {
#pragma unroll
        for (int j = 0; j < NSLOT; j++) {
            float a0 = 0.f, a1 = 0.f, a2 = 0.f, a3 = 0.f;
#pragma unroll
            for (int c = 0; c < 32; c += 4) {
                f32x4 sv = *(const f32x4*)(&S.slots[p][j][c]);
                a0 += sv[0] * S.WqT[c][l];     a1 += sv[1] * S.WqT[c + 1][l];
                a2 += sv[2] * S.WqT[c + 2][l]; a3 += sv[3] * S.WqT[c + 3][l];
            }
            S.qq[p][j][l] = elu1((S.bq[l] + ((a0 + a1) + (a2 + a3)) + S.initl[p][j][l]) * rs);
        }
        wb();
        if (l < 3 * NSLOT) {
            int i = l / NSLOT, j = l % NSLOT;
            float a0 = 0.f, a1 = 0.f, a2 = 0.f, a3 = 0.f;
#pragma unroll
            for (int c = 0; c < 32; c += 4) {
                f32x4 kv = *(const f32x4*)(&S.kk[p][i][c]);
                f32x4 qv = *(const f32x4*)(&S.qq[p][j][c]);
                a0 += kv[0] * qv[0]; a1 += kv[1] * qv[1];
                a2 += kv[2] * qv[2]; a3 += kv[3] * qv[3];
            }
            S.att[p][i][j] = (a0 + a1) + (a2 + a3);
        }
        wb();
        if (l < 3) {
            float mx = -1e30f;
            for (int j = 0; j < NSLOT; j++) mx = fmaxf(mx, S.att[p][l][j]);
            float sm = 0.f, ex[3];
            for (int j = 0; j < NSLOT; j++) { ex[j] = __expf(S.att[p][l][j] - mx); sm += ex[j]; }
            for (int j = 0; j < NSLOT; j++) S.att[p][l][j] = ex[j] / sm + 1e-8f;
        }
        wb();
        if (l < NSLOT) {
            float s = S.att[p][0][l] + S.att[p][1][l] + S.att[p][2][l];
            float inv = 1.0f / s;
            for (int i = 0; i < 3; i++) S.att[p][i][l] *= inv;
        }
        wb();
#pragma unroll
        for (int j = 0; j < NSLOT; j++) {
            float u = S.att[p][0][j] * S.vv[p][0][l] + S.att[p][1][j] * S.vv[p][1][l] + S.att[p][2][j] * S.vv[p][2][l];
            float mean = u;
            for (int mk = 1; mk < 32; mk <<= 1) mean += __shfl_xor(mean, mk, 32);
            mean *= (1.0f / 32.0f);
            float d = u - mean;
            float var = d * d;
            for (int mk = 1; mk < 32; mk <<= 1) var += __shfl_xor(var, mk, 32);
            var *= (1.0f / 32.0f);
            float y = d * rsqrtf(var + 1e-5f) * S.g[l] + S.be[l];
            S.ubuf[p][l] = y;
            wb();
#pragma unroll
            for (int oo = 0; oo < 2; oo++) {
                int o = l + oo * 32;
                float a0 = 0.f, a1 = 0.f, a2 = 0.f, a3 = 0.f;
#pragma unroll
                for (int c = 0; c < 32; c += 4) {
                    f32x4 uv = *(const f32x4*)(&S.ubuf[p][c]);
                    a0 += uv[0] * S.Wm1T[c][o];     a1 += uv[1] * S.Wm1T[c + 1][o];
                    a2 += uv[2] * S.Wm1T[c + 2][o]; a3 += uv[3] * S.Wm1T[c + 3][o];
                }
                S.hid[p][o] = fmaxf(S.bm1[o] + ((a0 + a1) + (a2 + a3)), 0.f);
            }
            wb();
            float a0 = 0.f, a1 = 0.f, a2 = 0.f, a3 = 0.f;
#pragma unroll
            for (int c = 0; c < 64; c += 4) {
                f32x4 hv = *(const f32x4*)(&S.hid[p][c]);
                a0 += hv[0] * S.Wm2T[c][l];     a1 += hv[1] * S.Wm2T[c + 1][l];
                a2 += hv[2] * S.Wm2T[c + 2][l]; a3 += hv[3] * S.Wm2T[c + 3][l];
            }
            S.slots[p][j][l] += (S.bm2[l] + ((a0 + a1) + (a2 + a3))) * (1.0f / 32.0f);
            wb();
        }
    }
    float pj[NSLOT];
#pragma unroll
    for (int j = 0; j < NSLOT; j++) {
        float a0 = 0.f, a1 = 0.f, a2 = 0.f, a3 = 0.f;
#pragma unroll
        for (int c = 0; c < 32; c += 4) {
            f32x4 iv = *(const f32x4*)(&S.initl[p][j][c]);
            a0 += iv[0] * S.WspT[c][l];     a1 += iv[1] * S.WspT[c + 1][l];
            a2 += iv[2] * S.WspT[c + 2][l]; a3 += iv[3] * S.WspT[c + 3][l];
        }
#pragma unroll
        for (int c = 0; c < 32; c += 4) {
            f32x4 sv = *(const f32x4*)(&S.slots[p][j][c]);
            a0 += sv[0] * S.WspT[32 + c][l];     a1 += sv[1] * S.WspT[32 + c + 1][l];
            a2 += sv[2] * S.WspT[32 + c + 2][l]; a3 += sv[3] * S.WspT[32 + c + 3][l];
        }
        pj[j] = S.bsp[l] + ((a0 + a1) + (a2 + a3));
    }
    const float e = 1e-6f, me = (float)(1.0 - 2e-6);
    if (NSLOT == 3) {
        ag_storef(&o1[row * 32 + l], tanhf(me * pj[0] + e * pj[1] + e * pj[2]));
        ag_storef(&o2[row * 32 + l], tanhf(e * pj[0] + me * pj[1] + e * pj[2]));
        ag_storef(&o3[row * 32 + l], tanhf(e * pj[0] + e * pj[1] + me * pj[2]));
    } else {
        ag_storef(&o1[row * 32 + l], tanhf(me * pj[0] + e * pj[1]));
        ag_storef(&o2[row * 32 + l], tanhf(e * pj[0] + me * pj[1]));
    }
}

// ---------------------------------------------------------------------------
// Mega kernel, 256 blocks (exactly 1/CU) — R13 champion structure with 64
// workers (R19-validated grid/scan shape, R17-validated slot math, LDS
// weights). Model: mega-end ~= max(worker completion 8192/64*24.5 ~= 3136us,
// 2660 + 0.16*window ~= 3162us) -> ~3140-3190, slightly better than R13's
// 63-worker 3187.
//   flags: f0 @0, f1 @4096, f1s @8192, prog @12288 (64 x stride-16)
// ---------------------------------------------------------------------------
__global__ __launch_bounds__(256) void k_mega(
    const u16* __restrict__ emb,
    const u16* __restrict__ Wx0, const u16* __restrict__ Wh0,
    const u16* __restrict__ Wx1, const u16* __restrict__ Wh1,
    const float* __restrict__ bi0, const float* __restrict__ bh0,
    const float* __restrict__ bi1, const float* __restrict__ bh1,
    u16* __restrict__ h0seq,        // [512][64][64][8] block-major
    u16* __restrict__ h1seq,        // [512][64][64][8] block-major
    u16* __restrict__ acat,         // [32768][544]; cols 0..511 h1, 512.. scan out
    int* __restrict__ flags,
    float* __restrict__ r1, float* __restrict__ r2,
    float* __restrict__ fi, float* __restrict__ uu1, float* __restrict__ uu2,
    const float* __restrict__ Wg, const float* __restrict__ bg,
    const u16* __restrict__ dec,
    const u16* __restrict__ initb, const u16* __restrict__ initr,
    const float* __restrict__ Wq, const float* __restrict__ bq,
    const float* __restrict__ Wk, const float* __restrict__ bk,
    const float* __restrict__ Wv, const float* __restrict__ bv,
    const float* __restrict__ lng, const float* __restrict__ lnb,
    const float* __restrict__ Wm1, const float* __restrict__ bm1,
    const float* __restrict__ Wm2, const float* __restrict__ bm2,
    const float* __restrict__ Wsp, const float* __restrict__ bsp)
{
    __shared__ SmemU sm;
    const int tid = threadIdx.x;
    const int blk = blockIdx.x;
    int* f0   = flags;
    int* f1   = flags + 4096;
    int* f1s  = flags + 8192;
    int* prog = flags + 12288;

    if (blk < 128) {
        // =================== wave-autonomous LSTM (R10 verbatim) ==========
        auto& Wx = sm.l.Wx;
        auto& Wh = sm.l.Wh;
        auto& zs = sm.l.zs;
        const int layer = blk >> 6;
        const int me = blk & 63;
        const int jbase = me * 8;
        const int Kx = layer ? 512 : 256;
        const u16* Wxp = layer ? Wx1 : Wx0;
        const u16* Whp = layer ? Wh1 : Wh0;
        const float* bi = layer ? bi1 : bi0;
        const float* bh = layer ? bh1 : bh0;
#pragma unroll
        for (int i = 0; i < 8; i++) {
            int c = tid + i * 256;
            int row = c >> 6, cc = (c & 63) * 8;
            int grow = (row >> 3) * 512 + jbase + (row & 7);
            *(uint4*)(&Wh[row][cc]) = *(const uint4*)(Whp + (size_t)grow * 512 + cc);
        }
        {
            int cpr = Kx >> 3;
            int iters = (32 * cpr) >> 8;
            for (int i = 0; i < iters; i++) {
                int c = tid + i * 256;
                int row = c / cpr, cc = (c % cpr) * 8;
                int grow = (row >> 3) * 512 + jbase + (row & 7);
                *(uint4*)(&Wx[row][cc]) = *(const uint4*)(Wxp + (size_t)grow * Kx + cc);
            }
        }
        const int wave = tid >> 6, lane = tid & 63;
        const int quad = lane >> 4, l16 = lane & 15;
        const int m = wave * 16 + l16;
        const int bl = lane >> 2;
        const int b = wave * 16 + bl;
        const int jj = (lane & 3) * 2;
        const int hoff = quad * 512 + m * 8;
        float bia0[4], bia1[4];
#pragma unroll
        for (int g = 0; g < 4; g++) {
            bia0[g] = bi[g * 512 + jbase + jj]     + bh[g * 512 + jbase + jj];
            bia1[g] = bi[g * 512 + jbase + jj + 1] + bh[g * 512 + jbase + jj + 1];
        }
        const int pollOwn = (wave * 64 + lane) * 16;
        const int pubIdx  = (wave * 64 + me) * 16;
        float c0 = 0.f, c1 = 0.f;
        __syncthreads();
        for (int t = 0; t < 512; t++) {
            f32x4 acc0 = {}, acc1 = {};
            if (!layer) {
                const u16* xrow = emb + ((size_t)t * 64 + m) * 256;
#pragma unroll
                for (int kc = 0; kc < 8; kc++) {
                    bf16x8 a  = *(const bf16x8*)(xrow + kc * 32 + quad * 8);
                    bf16x8 w0 = *(const bf16x8*)(&Wx[l16][kc * 32 + quad * 8]);
                    bf16x8 w1 = *(const bf16x8*)(&Wx[16 + l16][kc * 32 + quad * 8]);
                    acc0 = __builtin_amdgcn_mfma_f32_16x16x32_bf16(a, w0, acc0, 0, 0, 0);
                    acc1 = __builtin_amdgcn_mfma_f32_16x16x32_bf16(a, w1, acc1, 0, 0, 0);
                }
                if (t > 0) {
                    int it = 0;
                    for (;;) {
                        int a = ag_load(f0 + pollOwn);
                        if (__all(a >= t)) break;
                        if (++it > 3000000) break;
                        __builtin_amdgcn_s_sleep(1);
                    }
                    const u16* hrd = h0seq + (size_t)(t - 1) * 32768 + hoff;
#pragma unroll
                    for (int kc = 0; kc < 16; kc++) {
                        bf16x8 a  = *(const bf16x8*)(hrd + kc * 2048);
                        bf16x8 w0 = *(const bf16x8*)(&Wh[l16][kc * 32 + quad * 8]);
                        bf16x8 w1 = *(const bf16x8*)(&Wh[16 + l16][kc * 32 + quad * 8]);
                        acc0 = __builtin_amdgcn_mfma_f32_16x16x32_bf16(a, w0, acc0, 0, 0, 0);
                        acc1 = __builtin_amdgcn_mfma_f32_16x16x32_bf16(a, w1, acc1, 0, 0, 0);
                    }
                }
            } else {
                {
                    int it = 0;
                    for (;;) {
                        int a = ag_load(f0 + pollOwn);
                        if (__all(a >= t + 1)) break;
                        if (++it > 3000000) break;
                        __builtin_amdgcn_s_sleep(1);
                    }
                }
                const u16* xrow = h0seq + (size_t)t * 32768 + hoff;
#pragma unroll
                for (int kc = 0; kc < 16; kc++) {
                    bf16x8 a  = *(const bf16x8*)(xrow + kc * 2048);
                    bf16x8 w0 = *(const bf16x8*)(&Wx[l16][kc * 32 + quad * 8]);
                    bf16x8 w1 = *(const bf16x8*)(&Wx[16 + l16][kc * 32 + quad * 8]);
                    acc0 = __builtin_amdgcn_mfma_f32_16x16x32_bf16(a, w0, acc0, 0, 0, 0);
                    acc1 = __builtin_amdgcn_mfma_f32_16x16x32_bf16(a, w1, acc1, 0, 0, 0);
                }
                if (t > 0) {
                    int it = 0;
                    for (;;) {
                        int a = ag_load(f1 + pollOwn);
                        if (__all(a >= t)) break;
                        if (++it > 3000000) break;
                        __builtin_amdgcn_s_sleep(1);
                    }
                    const u16* hrd = h1seq + (size_t)(t - 1) * 32768 + hoff;
#pragma unroll
                    for (int kc = 0; kc < 16; kc++) {
                        bf16x8 a  = *(const bf16x8*)(hrd + kc * 2048);
                        bf16x8 w0 = *(const bf16x8*)(&Wh[l16][kc * 32 + quad * 8]);
                        bf16x8 w1 = *(const bf16x8*)(&Wh[16 + l16][kc * 32 + quad * 8]);
                        acc0 = __builtin_amdgcn_mfma_f32_16x16x32_bf16(a, w0, acc0, 0, 0, 0);
                        acc1 = __builtin_amdgcn_mfma_f32_16x16x32_bf16(a, w1, acc1, 0, 0, 0);
                    }
                }
            }
#pragma unroll
            for (int r = 0; r < 4; r++) {
                zs[wave][quad * 4 + r][l16]      = acc0[r];
                zs[wave][quad * 4 + r][16 + l16] = acc1[r];
            }
            u16 hb0, hb1;
            {
                float zi0 = zs[wave][bl][jj]      + bia0[0];
                float zf0 = zs[wave][bl][8 + jj]  + bia0[1];
                float zg0 = zs[wave][bl][16 + jj] + bia0[2];
                float zo0 = zs[wave][bl][24 + jj] + bia0[3];
                c0 = sigm(zf0) * c0 + sigm(zi0) * tanhf(zg0);
                float h0v = sigm(zo0) * tanhf(c0);
                float zi1 = zs[wave][bl][jj + 1]      + bia1[0];
                float zf1 = zs[wave][bl][8 + jj + 1]  + bia1[1];
                float zg1 = zs[wave][bl][16 + jj + 1] + bia1[2];
                float zo1 = zs[wave][bl][24 + jj + 1] + bia1[3];
                c1 = sigm(zf1) * c1 + sigm(zi1) * tanhf(zg1);
                float h1v = sigm(zo1) * tanhf(c1);
                hb0 = f2bf(h0v); hb1 = f2bf(h1v);
            }
            if (!layer) {
                llc_store2(h0seq + (size_t)t * 32768 + me * 512 + b * 8 + jj, hb0, hb1);
                __builtin_amdgcn_s_waitcnt(0);
                if (lane == 0) ag_store(f0 + pubIdx, t + 1);
            } else {
                llc_store2(h1seq + (size_t)t * 32768 + me * 512 + b * 8 + jj, hb0, hb1);
                __builtin_amdgcn_s_waitcnt(0);
                if (lane == 0) ag_store(f1 + pubIdx, t + 1);
                llc_store2(acat + ((size_t)t * 64 + b) * 544 + jbase + jj, hb0, hb1);
                __builtin_amdgcn_s_waitcnt(0);
                if (lane == 0) ag_store(f1s + pubIdx, t + 1);
            }
        }
    } else if (blk < 192) {
        // =================== trailing scan + inline gate ==================
        const int sb = blk - 128;
        const int grp = sb >> 4;
        const int f = tid & 31, rg = tid >> 5;
        float m[4][32];
#pragma unroll
        for (int x = 0; x < 4; x++)
            for (int y = 0; y < 32; y++) m[x][y] = 0.f;
        auto& r1s = sm.c.r1s;
        auto& r2s = sm.c.r2s;
        auto& fis = sm.c.fis;
        auto& u1s = sm.c.u1s;
        auto& u2s = sm.c.u2s;
        auto& red = sm.c.red;
        auto& wred = sm.c.wred;
        auto& gpart = sm.c.gpart;
        float wg0 = Wg[2 * tid], wg1 = Wg[2 * tid + 1];
        float bgv = bg[0];
        for (int t = 0; t < 512; t++) {
            // dual gate: wave0 polls LSTM f1s; wave1 polls worker progress
            if (tid < 64) {
                int* p1 = f1s + (grp * 64 + tid) * 16;
                int it = 0;
                for (;;) {
                    int a = ag_load(p1);
                    if (__all(a >= t + 1)) break;
                    if (++it > 3000000) break;
                    __builtin_amdgcn_s_sleep(1);
                }
            } else if (tid < 128) {
                const int k = tid - 64;
                const int* pp = prog + k * 16;
                const int need = (t + 1) * 16;
                int it = 0;
                for (;;) {
                    int a = ag_load(pp);
                    if (__all(a >= need)) break;
                    if (++it > 3000000) break;
                    __builtin_amdgcn_s_sleep(1);
                }
            }
            __syncthreads();
            // preloads AFTER the gates (R13-validated ordering)
            float pre = 0.f;
            {
                size_t base = ((size_t)t * 64 + sb) * 32;
                if (tid < 32) pre = r1[base + tid];
                else if (tid < 64) pre = r2[base + tid - 32];
                else if (tid < 96) pre = fi[base + tid - 64];
                else if (tid < 128) pre = uu1[base + tid - 96];
                else if (tid < 160) pre = uu2[base + tid - 128];
            }
            {
                const u16* hr = acat + ((size_t)t * 64 + sb) * 544;
                u32 hv = *(const u32*)(hr + 2 * tid);
                float gp = bf2f((u16)hv) * wg0 + bf2f((u16)(hv >> 16)) * wg1;
                for (int mk = 1; mk < 64; mk <<= 1) gp += __shfl_xor(gp, mk, 64);
                if ((tid & 63) == 0) gpart[tid >> 6] = gp;
            }
            if (tid < 32) r1s[tid] = pre;
            else if (tid < 64) r2s[tid - 32] = pre;
            else if (tid < 96) fis[tid - 64] = pre;
            else if (tid < 128) u1s[tid - 96] = pre;
            else if (tid < 160) u2s[tid - 128] = pre;
            __syncthreads();
            float gsh = sigm(gpart[0] + gpart[1] + gpart[2] + gpart[3] + bgv + 1.0f);
            float p = 0.f;
#pragma unroll
            for (int rl = 0; rl < 4; rl++) {
                float s = 0.f;
                for (int ti = 0; ti < 32; ti++) s += r2s[ti] * m[rl][ti];
                p += r1s[rg * 4 + rl] * s;
            }
            red[rg][f] = p;
            __syncthreads();
            float prev = 0.f;
#pragma unroll
            for (int g = 0; g < 8; g++) prev += red[g][f];
            float curo = gsh * (fis[f] - prev) * (1.0f / 32.0f);
            float nsq = 0.f;
#pragma unroll
            for (int rl = 0; rl < 4; rl++) {
                float a = r1s[rg * 4 + rl] * curo;
                for (int ti = 0; ti < 32; ti++) {
                    m[rl][ti] += a * r2s[ti];
                    nsq += m[rl][ti] * m[rl][ti];
                }
            }
            for (int mk = 1; mk < 64; mk <<= 1) nsq += __shfl_xor(nsq, mk, 64);
            __syncthreads();
            if ((tid & 63) == 0) wred[tid >> 6] = nsq;
            __syncthreads();
            float nrm = sqrtf(wred[0] + wred[1] + wred[2] + wred[3]);
            float sc = nrm > 1.0f ? 1.0f / nrm : 1.0f;
            float rp = 0.f;
#pragma unroll
            for (int rl = 0; rl < 4; rl++) {
                float s = 0.f;
                for (int ti = 0; ti < 32; ti++) {
                    m[rl][ti] *= sc;
                    s += m[rl][ti] * u2s[ti];
                }
                rp += u1s[rg * 4 + rl] * s;
            }
            red[rg][f] = rp;
            __syncthreads();
            float rv = 0.f;
#pragma unroll
            for (int g = 0; g < 8; g++) rv += red[g][f];
            float mean = rv;
            for (int mk = 1; mk < 32; mk <<= 1) mean += __shfl_xor(mean, mk, 32);
            mean *= (1.0f / 32.0f);
            float d = rv - mean;
            float var = d * d;
            for (int mk = 1; mk < 32; mk <<= 1) var += __shfl_xor(var, mk, 32);
            var *= (1.0f / 32.0f);
            if (tid < 32) {
                float y = d * rsqrtf(var + 1e-5f);
                llc_store_u16(acat + ((size_t)t * 64 + sb) * 544 + 512 + f, f2bf(y));
            }
            __syncthreads();
        }
    } else {
        // =================== slot workers (blk 192..255, own CUs) =========
        const int wid = blk - 192;   // 0..63
        stage_slot_weights(sm.s, tid, Wq, bq, Wk, bk, Wv, bv, lng, lnb,
                           Wm1, bm1, Wm2, bm2, Wsp, bsp);
        __syncthreads();
        int* myprog = prog + wid * 16;
        for (int u = wid; u < 8192; u += 64) {
            const int t = u >> 4, s = u & 15;
            if (s < 8)
                slot_unit<3>(sm.s, tid, (size_t)t * 64 + s * 8, dec, initb, r1, r2, fi);
            else
                slot_unit<2>(sm.s, tid, (size_t)t * 64 + (s - 8) * 8, dec, initr, uu1, uu2, nullptr);
            __builtin_amdgcn_s_waitcnt(0);   // output stores acked at LLC
            __syncthreads();                 // LDS reusable
            if (tid == 0) ag_store(myprog, u + 64);   // no pending unit < u+64
        }
    }
}

// ---------------------------------------------------------------------------
extern "C" void kernel_launch(void* const* d_in, const int* in_sizes, int n_in,
                              void* d_out, int out_size, void* d_ws, size_t ws_size,
                              hipStream_t stream)
{
    (void)in_sizes; (void)n_in; (void)out_size; (void)ws_size;
    const int*   tokens = (const int*)d_in[0];
    const float* embW  = (const float*)d_in[1];
    const float* Wih0  = (const float*)d_in[2];
    const float* Whh0  = (const float*)d_in[3];
    const float* bih0  = (const float*)d_in[4];
    const float* bhh0  = (const float*)d_in[5];
    const float* Wih1  = (const float*)d_in[6];
    const float* Whh1  = (const float*)d_in[7];
    const float* bih1  = (const float*)d_in[8];
    const float* bhh1  = (const float*)d_in[9];
    const float* Wpi   = (const float*)d_in[10];
    const float* bpi   = (const float*)d_in[11];
    const float* Wq    = (const float*)d_in[12];
    const float* bq    = (const float*)d_in[13];
    const float* Wk    = (const float*)d_in[14];
    const float* bk    = (const float*)d_in[15];
    const float* Wv    = (const float*)d_in[16];
    const float* bv    = (const float*)d_in[17];
    const float* lng   = (const float*)d_in[18];
    const float* lnb   = (const float*)d_in[19];
    const float* Wm1   = (const float*)d_in[20];
    const float* bm1   = (const float*)d_in[21];
    const float* Wm2   = (const float*)d_in[22];
    const float* bm2   = (const float*)d_in[23];
    const float* Wbind = (const float*)d_in[24];
    const float* bbind = (const float*)d_in[25];
    const float* Wreas = (const float*)d_in[26];
    const float* breas = (const float*)d_in[27];
    const float* Wsp   = (const float*)d_in[28];
    const float* bsp   = (const float*)d_in[29];
    const float* Wg    = (const float*)d_in[30];
    const float* bg    = (const float*)d_in[31];
    const float* Wout  = (const float*)d_in[32];
    const float* bout  = (const float*)d_in[33];

    char* ws = (char*)d_ws;
    size_t off = 0;
    auto alloc = [&](size_t bytes) { size_t o = off; off += (bytes + 255) & ~(size_t)255; return o; };
    int*  flags  = (int*)(ws + alloc(16384 * 4));   // f0, f1, f1s, prog
    u16*  emb    = (u16*)(ws + alloc(32768ull * 256 * 2));
    u16*  dec    = (u16*)(ws + alloc(32768ull * 192 * 2));
    u16*  initb  = (u16*)(ws + alloc(32768ull * 96 * 2));
    u16*  initr  = (u16*)(ws + alloc(32768ull * 64 * 2));
    u16*  acat   = (u16*)(ws + alloc(32768ull * 544 * 2));
    u16*  h0seq  = (u16*)(ws + alloc(512ull * 64 * 512 * 2));
    u16*  h1seq  = (u16*)(ws + alloc(512ull * 64 * 512 * 2));
    float* role1 = (float*)(ws + alloc(32768ull * 32 * 4));
    float* role2 = (float*)(ws + alloc(32768ull * 32 * 4));
    float* fill  = (float*)(ws + alloc(32768ull * 32 * 4));
    float* u1v   = (float*)(ws + alloc(32768ull * 32 * 4));
    float* u2v   = (float*)(ws + alloc(32768ull * 32 * 4));
    u16* Wx0b  = (u16*)(ws + alloc(2048ull * 256 * 2));
    u16* Wh0b  = (u16*)(ws + alloc(2048ull * 512 * 2));
    u16* Wx1b  = (u16*)(ws + alloc(2048ull * 512 * 2));
    u16* Wh1b  = (u16*)(ws + alloc(2048ull * 512 * 2));
    u16* Wpib  = (u16*)(ws + alloc(192ull * 256 * 2));
    u16* Wbindb = (u16*)(ws + alloc(96ull * 192 * 2));
    u16* Wreasb = (u16*)(ws + alloc(64ull * 192 * 2));
    u16* Woutb  = (u16*)(ws + alloc(128ull * 544 * 2));

    hipMemsetAsync(flags, 0, 16384 * 4, stream);
    {
        Cvt8 c;
        const float* s[8] = {Wih0, Whh0, Wih1, Whh1, Wpi, Wbind, Wreas, Wout};
        u16* d[8] = {Wx0b, Wh0b, Wx1b, Wh1b, Wpib, Wbindb, Wreasb, Woutb};
        int n[8] = {2048 * 256, 2048 * 512, 2048 * 512, 2048 * 512,
                    192 * 256, 96 * 192, 64 * 192, 128 * 544};
        int acc = 0;
        for (int k = 0; k < 8; k++) { c.s[k] = s[k]; c.d[k] = d[k]; c.off4[k] = acc; acc += n[k] / 4; }
        c.off4[8] = acc;
        k_f2b8<<<(acc + 255) / 256, 256, 0, stream>>>(c);
    }
    k_embed<<<4096, 256, 0, stream>>>(tokens, embW, emb);
    k_gemm_bt<<<dim3(256, 2), 256, 0, stream>>>(emb, 256, Wpib, dec, nullptr, 192, bpi, nullptr, 192, 256);
    k_gemm_bt<<<dim3(256, 1), 256, 0, stream>>>(dec, 192, Wbindb, initb, nullptr, 96, bbind, nullptr, 96, 192);
    k_gemm_bt<<<dim3(256, 1), 256, 0, stream>>>(dec, 192, Wreasb, initr, nullptr, 64, breas, nullptr, 64, 192);
    // fused: LSTM + scan + 64 slot workers (1 block/CU; R13 structure)
    k_mega<<<256, 256, 0, stream>>>(emb, Wx0b, Wh0b, Wx1b, Wh1b,
                                    bih0, bhh0, bih1, bhh1,
                                    h0seq, h1seq, acat, flags,
                                    role1, role2, fill, u1v, u2v, Wg, bg,
                                    dec, initb, initr,
                                    Wq, bq, Wk, bk, Wv, bv, lng, lnb,
                                    Wm1, bm1, Wm2, bm2, Wsp, bsp);
    // out = acat @ Wout^T + bout  (fp32 output)
    k_gemm_bt<<<dim3(256, 1), 256, 0, stream>>>(acat, 544, Woutb, nullptr, (float*)d_out, 128, bout, nullptr, 128, 544);
}

// Round 14
// 3276.196 us; speedup vs baseline: 1.5293x; 1.2229x over previous
//
#include <hip/hip_runtime.h>

typedef unsigned short u16;
typedef unsigned int u32;
typedef unsigned long long u64;
typedef __bf16 bf16x8 __attribute__((ext_vector_type(8)));
typedef float f32x4 __attribute__((ext_vector_type(4)));

__device__ __forceinline__ float bf2f(u16 u) { return __uint_as_float(((u32)u) << 16); }
__device__ __forceinline__ u16 f2bf(float f) {
    u32 u = __float_as_uint(f);
    u32 r = (u + 0x7FFFu + ((u >> 16) & 1u)) >> 16;
    return (u16)r;
}
__device__ __forceinline__ float sigm(float x) { return 1.0f / (1.0f + __expf(-x)); }
__device__ __forceinline__ float elu1(float x) { return x > 0.0f ? x + 1.0f : __expf(x); }

// agent-scope (LLC) atomics — HW-validated cross-XCD path (R5/R7)
__device__ __forceinline__ int ag_load(const int* p) {
    return __hip_atomic_load(p, __ATOMIC_RELAXED, __HIP_MEMORY_SCOPE_AGENT);
}
__device__ __forceinline__ void ag_store(int* p, int v) {
    __hip_atomic_store(p, v, __ATOMIC_RELAXED, __HIP_MEMORY_SCOPE_AGENT);
}
__device__ __forceinline__ void ag_storef(float* p, float v) {
    __hip_atomic_store(p, v, __ATOMIC_RELAXED, __HIP_MEMORY_SCOPE_AGENT);
}
__device__ __forceinline__ void llc_store2(u16* p, u16 a, u16 b) {
    u32 v = (u32)a | ((u32)b << 16);
    __hip_atomic_store((u32*)p, v, __ATOMIC_RELAXED, __HIP_MEMORY_SCOPE_AGENT);
}
__device__ __forceinline__ void llc_store_u16(u16* p, u16 v) {
    __hip_atomic_store(p, v, __ATOMIC_RELAXED, __HIP_MEMORY_SCOPE_AGENT);
}

// ---------------------------------------------------------------------------
struct Cvt8 { const float* s[8]; u16* d[8]; int off4[9]; };

__global__ __launch_bounds__(256) void k_f2b8(Cvt8 c)
{
    int i = blockIdx.x * 256 + threadIdx.x;
    if (i >= c.off4[8]) return;
    int k = 0;
#pragma unroll
    for (int q = 1; q < 8; q++) if (i >= c.off4[q]) k = q;
    int j = i - c.off4[k];
    float4 v = ((const float4*)c.s[k])[j];
    ushort4 o;
    o.x = f2bf(v.x); o.y = f2bf(v.y); o.z = f2bf(v.z); o.w = f2bf(v.w);
    ((ushort4*)c.d[k])[j] = o;
}

// ---------------------------------------------------------------------------
__global__ __launch_bounds__(256) void k_embed(const int* __restrict__ tok,
                                               const float* __restrict__ W,
                                               u16* __restrict__ out)
{
    int c = blockIdx.x * 256 + threadIdx.x;
    int row = c >> 5, cc = (c & 31) * 8;
    int t = tok[row];
    const float* src = W + (size_t)t * 256 + cc;
    u16 tmp[8];
#pragma unroll
    for (int k = 0; k < 8; k++) tmp[k] = f2bf(src[k]);
    *(uint4*)(out + (size_t)row * 256 + cc) = *(uint4*)tmp;
}

// ---------------------------------------------------------------------------
// GEMM:  C[M,N] = A[M,K](bf16, lda) * B[N,K]^T(bf16) + bias. 128x128 tile.
// ---------------------------------------------------------------------------
__global__ __launch_bounds__(256) void k_gemm_bt(
    const u16* __restrict__ A, int lda,
    const u16* __restrict__ B,
    u16* __restrict__ Cb, float* __restrict__ Cf, int ldc,
    const float* __restrict__ bias1, const float* __restrict__ bias2,
    int N, int K)
{
    __shared__ u16 As[128][40];
    __shared__ u16 Bs[128][40];
    const int tid = threadIdx.x;
    const int m0 = blockIdx.x * 128, n0 = blockIdx.y * 128;
    const int wave = tid >> 6, lane = tid & 63;
    const int wm = wave & 1, wn = wave >> 1;
    const int quad = lane >> 4, l16 = lane & 15;
    f32x4 acc[4][4] = {};
    for (int k0 = 0; k0 < K; k0 += 32) {
        __syncthreads();
#pragma unroll
        for (int i = 0; i < 2; i++) {
            int c = tid + i * 256, row = c >> 2, cc = (c & 3) * 8;
            *(uint4*)(&As[row][cc]) = *(const uint4*)(A + (size_t)(m0 + row) * lda + k0 + cc);
            uint4 d = {0, 0, 0, 0};
            if (n0 + row < N) d = *(const uint4*)(B + (size_t)(n0 + row) * K + k0 + cc);
            *(uint4*)(&Bs[row][cc]) = d;
        }
        __syncthreads();
        bf16x8 af[4], bfm[4];
#pragma unroll
        for (int x = 0; x < 4; x++) {
            af[x]  = *(const bf16x8*)(&As[wm * 64 + x * 16 + l16][quad * 8]);
            bfm[x] = *(const bf16x8*)(&Bs[wn * 64 + x * 16 + l16][quad * 8]);
        }
#pragma unroll
        for (int mi = 0; mi < 4; mi++)
#pragma unroll
            for (int ni = 0; ni < 4; ni++)
                acc[mi][ni] = __builtin_amdgcn_mfma_f32_16x16x32_bf16(af[mi], bfm[ni], acc[mi][ni], 0, 0, 0);
    }
#pragma unroll
    for (int ni = 0; ni < 4; ni++) {
        int col = n0 + wn * 64 + ni * 16 + l16;
        if (col < N) {
            float bv = 0.f;
            if (bias1) bv += bias1[col];
            if (bias2) bv += bias2[col];
#pragma unroll
            for (int mi = 0; mi < 4; mi++) {
                int r0 = m0 + wm * 64 + mi * 16 + quad * 4;
#pragma unroll
                for (int r = 0; r < 4; r++) {
                    float v = acc[mi][ni][r] + bv;
                    if (Cb) Cb[(size_t)(r0 + r) * ldc + col] = f2bf(v);
                    else    Cf[(size_t)(r0 + r) * ldc + col] = v;
                }
            }
        }
    }
}

// ---------------------------------------------------------------------------
// Shared-memory union: one kernel, three block roles (LSTM / scan / slot).
// ---------------------------------------------------------------------------
struct SmemLstm {
    u16 Wx[32][528];
    u16 Wh[32][528];
    float zs[4][16][33];
};
struct SmemSlot {
    float WqT[32][33], WkT[64][33], WvT[64][33], Wm1T[32][65], Wm2T[64][33], WspT[64][33];
    float bq[32], bk[32], bv[32], bm1[64], bm2[32], bsp[32], g[32], be[32];
    u16 xbuf[8][192];
    float slots[8][3][32], initl[8][3][32], kk[8][3][32], vv[8][3][32], qq[8][3][32];
    float att[8][3][4];
    float ubuf[8][32];
    float hid[8][64];
};
struct SmemScan {
    float r1s[32], r2s[32], fis[32], u1s[32], u2s[32];
    float red[8][32];
    float wred[4];
    float gpart[4];
};
union SmemU {
    SmemLstm l;
    SmemSlot s;
    SmemScan c;
};

// ---------------------------------------------------------------------------
// Slot attention — weights staged ONCE per worker block (R9 restaged per
// unit: ~130x wasted staging). Unit = 8 rows; outputs via agent stores.
// ---------------------------------------------------------------------------
__device__ __forceinline__ void stage_slot_weights(SmemSlot& S, const int tid,
    const float* __restrict__ Wq, const float* __restrict__ bq,
    const float* __restrict__ Wk, const float* __restrict__ bk,
    const float* __restrict__ Wv, const float* __restrict__ bv,
    const float* __restrict__ lng, const float* __restrict__ lnb,
    const float* __restrict__ Wm1, const float* __restrict__ bm1,
    const float* __restrict__ Wm2, const float* __restrict__ bm2,
    const float* __restrict__ Wsp, const float* __restrict__ bsp)
{
    for (int i = tid; i < 1024; i += 256) { int o = i >> 5, c = i & 31; S.WqT[c][o] = Wq[o * 32 + c]; }
    for (int i = tid; i < 2048; i += 256) {
        int o6 = i >> 6, c6 = i & 63;
        S.WkT[c6][o6]  = Wk[o6 * 64 + c6];
        S.WvT[c6][o6]  = Wv[o6 * 64 + c6];
        S.Wm2T[c6][o6] = Wm2[o6 * 64 + c6];
        S.WspT[c6][o6] = Wsp[o6 * 64 + c6];
        int o5 = i >> 5, c5 = i & 31;
        S.Wm1T[c5][o5] = Wm1[o5 * 32 + c5];
    }
    if (tid < 32) {
        S.bq[tid] = bq[tid]; S.bk[tid] = bk[tid]; S.bv[tid] = bv[tid];
        S.bm2[tid] = bm2[tid]; S.bsp[tid] = bsp[tid];
        S.g[tid] = lng[tid]; S.be[tid] = lnb[tid];
    }
    if (tid < 64) S.bm1[tid] = bm1[tid];
}

template <int NSLOT>
__device__ __forceinline__ void slot_unit(
    SmemSlot& S, const int tid, const size_t row0,
    const u16* __restrict__ dec, const u16* __restrict__ initp,
    float* __restrict__ o1, float* __restrict__ o2, float* __restrict__ o3)
{
    const int p = tid >> 5, l = tid & 31;
    const size_t row = row0 + p;
    for (int i = l; i < 192; i += 32) S.xbuf[p][i] = dec[row * 192 + i];
    __syncthreads();
#pragma unroll
    for (int i = 0; i < 3; i++) {
        float aK = S.bk[l], aV = S.bv[l];
        for (int c = 0; c < 64; c++) {
            float x = bf2f(S.xbuf[p][i * 64 + c]);
            aK += x * S.WkT[c][l];
            aV += x * S.WvT[c][l];
        }
        S.kk[p][i][l] = elu1(aK);
        S.vv[p][i][l] = aV;
    }
#pragma unroll
    for (int j = 0; j < NSLOT; j++) {
        float iv = bf2f(initp[row * (NSLOT * 32) + j * 32 + l]);
        S.initl[p][j][l] = iv;
        S.slots[p][j][l] = iv;
    }
    __syncthreads();
    const float rs = 0.17677669529663687f;
    for (int it = 0; it < 3; it++) {
#pragma unroll
        for (int j = 0; j < NSLOT; j++) {
            float a = S.bq[l];
            for (int c = 0; c < 32; c++) a += S.slots[p][j][c] * S.WqT[c][l];
            S.qq[p][j][l] = elu1((a + S.initl[p][j][l]) * rs);
        }
        __syncthreads();
        if (l < 3 * NSLOT) {
            int i = l / NSLOT, j = l % NSLOT;
            float s = 0.f;
            for (int c = 0; c < 32; c++) s += S.kk[p][i][c] * S.qq[p][j][c];
            S.att[p][i][j] = s;
        }
        __syncthreads();
        if (l < 3) {
            float mx = -1e30f;
            for (int j = 0; j < NSLOT; j++) mx = fmaxf(mx, S.att[p][l][j]);
            float sm = 0.f, ex[3];
            for (int j = 0; j < NSLOT; j++) { ex[j] = __expf(S.att[p][l][j] - mx); sm += ex[j]; }
            for (int j = 0; j < NSLOT; j++) S.att[p][l][j] = ex[j] / sm + 1e-8f;
        }
        __syncthreads();
        if (l < NSLOT) {
            float s = S.att[p][0][l] + S.att[p][1][l] + S.att[p][2][l];
            float inv = 1.0f / s;
            for (int i = 0; i < 3; i++) S.att[p][i][l] *= inv;
        }
        __syncthreads();
#pragma unroll
        for (int j = 0; j < NSLOT; j++) {
            float u = S.att[p][0][j] * S.vv[p][0][l] + S.att[p][1][j] * S.vv[p][1][l] + S.att[p][2][j] * S.vv[p][2][l];
            float mean = u;
            for (int mk = 1; mk < 32; mk <<= 1) mean += __shfl_xor(mean, mk, 32);
            mean *= (1.0f / 32.0f);
            float d = u - mean;
            float var = d * d;
            for (int mk = 1; mk < 32; mk <<= 1) var += __shfl_xor(var, mk, 32);
            var *= (1.0f / 32.0f);
            float y = d * rsqrtf(var + 1e-5f) * S.g[l] + S.be[l];
            S.ubuf[p][l] = y;
            __syncthreads();
#pragma unroll
            for (int oo = 0; oo < 2; oo++) {
                int o = l + oo * 32;
                float a = S.bm1[o];
                for (int c = 0; c < 32; c++) a += S.ubuf[p][c] * S.Wm1T[c][o];
                S.hid[p][o] = fmaxf(a, 0.f);
            }
            __syncthreads();
            float a2 = S.bm2[l];
            for (int c = 0; c < 64; c++) a2 += S.hid[p][c] * S.Wm2T[c][l];
            S.slots[p][j][l] += a2 * (1.0f / 32.0f);
            __syncthreads();
        }
    }
    float pj[NSLOT];
#pragma unroll
    for (int j = 0; j < NSLOT; j++) {
        float a = S.bsp[l];
        for (int c = 0; c < 32; c++) a += S.initl[p][j][c] * S.WspT[c][l];
        for (int c = 0; c < 32; c++) a += S.slots[p][j][c] * S.WspT[32 + c][l];
        pj[j] = a;
    }
    const float e = 1e-6f, me = (float)(1.0 - 2e-6);
    if (NSLOT == 3) {
        ag_storef(&o1[row * 32 + l], tanhf(me * pj[0] + e * pj[1] + e * pj[2]));
        ag_storef(&o2[row * 32 + l], tanhf(e * pj[0] + me * pj[1] + e * pj[2]));
        ag_storef(&o3[row * 32 + l], tanhf(e * pj[0] + e * pj[1] + me * pj[2]));
    } else {
        ag_storef(&o1[row * 32 + l], tanhf(me * pj[0] + e * pj[1]));
        ag_storef(&o2[row * 32 + l], tanhf(e * pj[0] + me * pj[1]));
    }
}

// ---------------------------------------------------------------------------
// Mega kernel, 255 blocks (~1 per CU — CU-PARTITIONED roles):
//   0..127   wave-autonomous LSTM (R10 champion verbatim: block-major h,
//            per-(group,block) flag lines, parallel publishes, 64-line poll)
//   128..191 trailing scan + gate (dual gate: wave0 f1s, wave1 slot progress)
//   192..254 63 persistent slot workers, each on its OWN CU, sweeping 8192
//            units (u%63) in ascending-t order; weights staged once.
// Worker k publishes p[k]=u+63 ("no pending unit of mine < p[k]") on its own
// line; chunk t ready <=> min_k p[k] >= (t+1)*16 (16 units/chunk: 8 bind +
// 8 reas of rows 64t..64t+63).
//   flags: f0 @0, f1 @4096, f1s @8192, prog @12288 (63 x stride-16)
// CHAMPION configuration (R13: 3276us total, k_mega 3189us). Seven attempted
// improvements (R14-R20) all measured worse; holding this state.
// ---------------------------------------------------------------------------
__global__ __launch_bounds__(256) void k_mega(
    const u16* __restrict__ emb,
    const u16* __restrict__ Wx0, const u16* __restrict__ Wh0,
    const u16* __restrict__ Wx1, const u16* __restrict__ Wh1,
    const float* __restrict__ bi0, const float* __restrict__ bh0,
    const float* __restrict__ bi1, const float* __restrict__ bh1,
    u16* __restrict__ h0seq,        // [512][64][64][8] block-major
    u16* __restrict__ h1seq,        // [512][64][64][8] block-major
    u16* __restrict__ acat,         // [32768][544]; cols 0..511 h1, 512.. scan out
    int* __restrict__ flags,
    float* __restrict__ r1, float* __restrict__ r2,
    float* __restrict__ fi, float* __restrict__ uu1, float* __restrict__ uu2,
    const float* __restrict__ Wg, const float* __restrict__ bg,
    const u16* __restrict__ dec,
    const u16* __restrict__ initb, const u16* __restrict__ initr,
    const float* __restrict__ Wq, const float* __restrict__ bq,
    const float* __restrict__ Wk, const float* __restrict__ bk,
    const float* __restrict__ Wv, const float* __restrict__ bv,
    const float* __restrict__ lng, const float* __restrict__ lnb,
    const float* __restrict__ Wm1, const float* __restrict__ bm1,
    const float* __restrict__ Wm2, const float* __restrict__ bm2,
    const float* __restrict__ Wsp, const float* __restrict__ bsp)
{
    __shared__ SmemU sm;
    const int tid = threadIdx.x;
    const int blk = blockIdx.x;
    int* f0   = flags;
    int* f1   = flags + 4096;
    int* f1s  = flags + 8192;
    int* prog = flags + 12288;

    if (blk < 128) {
        // =================== wave-autonomous LSTM (R10 verbatim) ==========
        auto& Wx = sm.l.Wx;
        auto& Wh = sm.l.Wh;
        auto& zs = sm.l.zs;
        const int layer = blk >> 6;
        const int me = blk & 63;
        const int jbase = me * 8;
        const int Kx = layer ? 512 : 256;
        const u16* Wxp = layer ? Wx1 : Wx0;
        const u16* Whp = layer ? Wh1 : Wh0;
        const float* bi = layer ? bi1 : bi0;
        const float* bh = layer ? bh1 : bh0;
#pragma unroll
        for (int i = 0; i < 8; i++) {
            int c = tid + i * 256;
            int row = c >> 6, cc = (c & 63) * 8;
            int grow = (row >> 3) * 512 + jbase + (row & 7);
            *(uint4*)(&Wh[row][cc]) = *(const uint4*)(Whp + (size_t)grow * 512 + cc);
        }
        {
            int cpr = Kx >> 3;
            int iters = (32 * cpr) >> 8;
            for (int i = 0; i < iters; i++) {
                int c = tid + i * 256;
                int row = c / cpr, cc = (c % cpr) * 8;
                int grow = (row >> 3) * 512 + jbase + (row & 7);
                *(uint4*)(&Wx[row][cc]) = *(const uint4*)(Wxp + (size_t)grow * Kx + cc);
            }
        }
        const int wave = tid >> 6, lane = tid & 63;
        const int quad = lane >> 4, l16 = lane & 15;
        const int m = wave * 16 + l16;       // global batch row for MFMA A-load
        const int bl = lane >> 2;            // local batch (0..15)
        const int b = wave * 16 + bl;        // global batch for elementwise
        const int jj = (lane & 3) * 2;       // local col pair
        const int hoff = quad * 512 + m * 8; // block-major read offset (elements)
        float bia0[4], bia1[4];
#pragma unroll
        for (int g = 0; g < 4; g++) {
            bia0[g] = bi[g * 512 + jbase + jj]     + bh[g * 512 + jbase + jj];
            bia1[g] = bi[g * 512 + jbase + jj + 1] + bh[g * 512 + jbase + jj + 1];
        }
        const int pollOwn = (wave * 64 + lane) * 16;   // lane polls block `lane`, group `wave`
        const int pubIdx  = (wave * 64 + me) * 16;
        float c0 = 0.f, c1 = 0.f;
        __syncthreads();   // Wx/Wh staged; last barrier before the loop
        for (int t = 0; t < 512; t++) {
            f32x4 acc0 = {}, acc1 = {};
            if (!layer) {
                // x-part (emb, independent of flags)
                const u16* xrow = emb + ((size_t)t * 64 + m) * 256;
#pragma unroll
                for (int kc = 0; kc < 8; kc++) {
                    bf16x8 a  = *(const bf16x8*)(xrow + kc * 32 + quad * 8);
                    bf16x8 w0 = *(const bf16x8*)(&Wx[l16][kc * 32 + quad * 8]);
                    bf16x8 w1 = *(const bf16x8*)(&Wx[16 + l16][kc * 32 + quad * 8]);
                    acc0 = __builtin_amdgcn_mfma_f32_16x16x32_bf16(a, w0, acc0, 0, 0, 0);
                    acc1 = __builtin_amdgcn_mfma_f32_16x16x32_bf16(a, w1, acc1, 0, 0, 0);
                }
                if (t > 0) {   // wait for group-w h0[t-1]
                    int it = 0;
                    for (;;) {
                        int a = ag_load(f0 + pollOwn);
                        if (__all(a >= t)) break;
                        if (++it > 3000000) break;
                        __builtin_amdgcn_s_sleep(1);
                    }
                    const u16* hrd = h0seq + (size_t)(t - 1) * 32768 + hoff;
#pragma unroll
                    for (int kc = 0; kc < 16; kc++) {
                        bf16x8 a  = *(const bf16x8*)(hrd + kc * 2048);
                        bf16x8 w0 = *(const bf16x8*)(&Wh[l16][kc * 32 + quad * 8]);
                        bf16x8 w1 = *(const bf16x8*)(&Wh[16 + l16][kc * 32 + quad * 8]);
                        acc0 = __builtin_amdgcn_mfma_f32_16x16x32_bf16(a, w0, acc0, 0, 0, 0);
                        acc1 = __builtin_amdgcn_mfma_f32_16x16x32_bf16(a, w1, acc1, 0, 0, 0);
                    }
                }
            } else {
                // wait for h0[t] (f0 group w >= t+1), then x-part
                {
                    int it = 0;
                    for (;;) {
                        int a = ag_load(f0 + pollOwn);
                        if (__all(a >= t + 1)) break;
                        if (++it > 3000000) break;
                        __builtin_amdgcn_s_sleep(1);
                    }
                }
                const u16* xrow = h0seq + (size_t)t * 32768 + hoff;
#pragma unroll
                for (int kc = 0; kc < 16; kc++) {
                    bf16x8 a  = *(const bf16x8*)(xrow + kc * 2048);
                    bf16x8 w0 = *(const bf16x8*)(&Wx[l16][kc * 32 + quad * 8]);
                    bf16x8 w1 = *(const bf16x8*)(&Wx[16 + l16][kc * 32 + quad * 8]);
                    acc0 = __builtin_amdgcn_mfma_f32_16x16x32_bf16(a, w0, acc0, 0, 0, 0);
                    acc1 = __builtin_amdgcn_mfma_f32_16x16x32_bf16(a, w1, acc1, 0, 0, 0);
                }
                if (t > 0) {   // wait for group-w h1[t-1], then h-part
                    int it = 0;
                    for (;;) {
                        int a = ag_load(f1 + pollOwn);
                        if (__all(a >= t)) break;
                        if (++it > 3000000) break;
                        __builtin_amdgcn_s_sleep(1);
                    }
                    const u16* hrd = h1seq + (size_t)(t - 1) * 32768 + hoff;
#pragma unroll
                    for (int kc = 0; kc < 16; kc++) {
                        bf16x8 a  = *(const bf16x8*)(hrd + kc * 2048);
                        bf16x8 w0 = *(const bf16x8*)(&Wh[l16][kc * 32 + quad * 8]);
                        bf16x8 w1 = *(const bf16x8*)(&Wh[16 + l16][kc * 32 + quad * 8]);
                        acc0 = __builtin_amdgcn_mfma_f32_16x16x32_bf16(a, w0, acc0, 0, 0, 0);
                        acc1 = __builtin_amdgcn_mfma_f32_16x16x32_bf16(a, w1, acc1, 0, 0, 0);
                    }
                }
            }
            // wave-local z staging (no barrier: same-wave LDS, lgkmcnt only)
#pragma unroll
            for (int r = 0; r < 4; r++) {
                zs[wave][quad * 4 + r][l16]      = acc0[r];
                zs[wave][quad * 4 + r][16 + l16] = acc1[r];
            }
            u16 hb0, hb1;
            {
                float zi0 = zs[wave][bl][jj]      + bia0[0];
                float zf0 = zs[wave][bl][8 + jj]  + bia0[1];
                float zg0 = zs[wave][bl][16 + jj] + bia0[2];
                float zo0 = zs[wave][bl][24 + jj] + bia0[3];
                c0 = sigm(zf0) * c0 + sigm(zi0) * tanhf(zg0);
                float h0v = sigm(zo0) * tanhf(c0);
                float zi1 = zs[wave][bl][jj + 1]      + bia1[0];
                float zf1 = zs[wave][bl][8 + jj + 1]  + bia1[1];
                float zg1 = zs[wave][bl][16 + jj + 1] + bia1[2];
                float zo1 = zs[wave][bl][24 + jj + 1] + bia1[3];
                c1 = sigm(zf1) * c1 + sigm(zi1) * tanhf(zg1);
                float h1v = sigm(zo1) * tanhf(c1);
                hb0 = f2bf(h0v); hb1 = f2bf(h1v);
            }
            if (!layer) {
                // block-major contiguous store: wave writes 256 B (4 full lines)
                llc_store2(h0seq + (size_t)t * 32768 + me * 512 + b * 8 + jj, hb0, hb1);
                __builtin_amdgcn_s_waitcnt(0);
                if (lane == 0) ag_store(f0 + pubIdx, t + 1);
            } else {
                llc_store2(h1seq + (size_t)t * 32768 + me * 512 + b * 8 + jj, hb0, hb1);
                __builtin_amdgcn_s_waitcnt(0);   // drain recurrence copy only
                if (lane == 0) ag_store(f1 + pubIdx, t + 1);
                // row-major copy for scan gate + final GEMM (off critical path)
                llc_store2(acat + ((size_t)t * 64 + b) * 544 + jbase + jj, hb0, hb1);
                __builtin_amdgcn_s_waitcnt(0);
                if (lane == 0) ag_store(f1s + pubIdx, t + 1);
            }
        }
    } else if (blk < 192) {
        // =================== trailing scan + inline gate ==================
        const int sb = blk - 128;          // batch
        const int grp = sb >> 4;           // its batch group
        const int f = tid & 31, rg = tid >> 5;
        float m[4][32];
#pragma unroll
        for (int x = 0; x < 4; x++)
            for (int y = 0; y < 32; y++) m[x][y] = 0.f;
        auto& r1s = sm.c.r1s;
        auto& r2s = sm.c.r2s;
        auto& fis = sm.c.fis;
        auto& u1s = sm.c.u1s;
        auto& u2s = sm.c.u2s;
        auto& red = sm.c.red;
        auto& wred = sm.c.wred;
        auto& gpart = sm.c.gpart;
        float wg0 = Wg[2 * tid], wg1 = Wg[2 * tid + 1];
        float bgv = bg[0];
        for (int t = 0; t < 512; t++) {
            // dual gate: wave0 polls LSTM f1s; wave1 polls slot worker progress
            if (tid < 64) {
                int* p1 = f1s + (grp * 64 + tid) * 16;
                int it = 0;
                for (;;) {
                    int a = ag_load(p1);
                    if (__all(a >= t + 1)) break;
                    if (++it > 3000000) break;
                    __builtin_amdgcn_s_sleep(1);
                }
            } else if (tid < 128) {
                const int k = tid - 64;
                const int* pp = prog + k * 16;
                const int need = (t + 1) * 16;
                int it = 0;
                for (;;) {
                    int a = 0x7FFFFFFF;
                    if (k < 63) a = ag_load(pp);
                    if (__all(a >= need)) break;
                    if (++it > 3000000) break;
                    __builtin_amdgcn_s_sleep(1);
                }
            }
            __syncthreads();
            // preloads AFTER the gates (slot outputs are produced concurrently)
            float pre = 0.f;
            {
                size_t base = ((size_t)t * 64 + sb) * 32;
                if (tid < 32) pre = r1[base + tid];
                else if (tid < 64) pre = r2[base + tid - 32];
                else if (tid < 96) pre = fi[base + tid - 64];
                else if (tid < 128) pre = uu1[base + tid - 96];
                else if (tid < 160) pre = uu2[base + tid - 128];
            }
            {
                const u16* hr = acat + ((size_t)t * 64 + sb) * 544;
                u32 hv = *(const u32*)(hr + 2 * tid);
                float gp = bf2f((u16)hv) * wg0 + bf2f((u16)(hv >> 16)) * wg1;
                for (int mk = 1; mk < 64; mk <<= 1) gp += __shfl_xor(gp, mk, 64);
                if ((tid & 63) == 0) gpart[tid >> 6] = gp;
            }
            if (tid < 32) r1s[tid] = pre;
            else if (tid < 64) r2s[tid - 32] = pre;
            else if (tid < 96) fis[tid - 64] = pre;
            else if (tid < 128) u1s[tid - 96] = pre;
            else if (tid < 160) u2s[tid - 128] = pre;
            __syncthreads();
            float gsh = sigm(gpart[0] + gpart[1] + gpart[2] + gpart[3] + bgv + 1.0f);
            float p = 0.f;
#pragma unroll
            for (int rl = 0; rl < 4; rl++) {
                float s = 0.f;
                for (int ti = 0; ti < 32; ti++) s += r2s[ti] * m[rl][ti];
                p += r1s[rg * 4 + rl] * s;
            }
            red[rg][f] = p;
            __syncthreads();
            float prev = 0.f;
#pragma unroll
            for (int g = 0; g < 8; g++) prev += red[g][f];
            float curo = gsh * (fis[f] - prev) * (1.0f / 32.0f);
            float nsq = 0.f;
#pragma unroll
            for (int rl = 0; rl < 4; rl++) {
                float a = r1s[rg * 4 + rl] * curo;
                for (int ti = 0; ti < 32; ti++) {
                    m[rl][ti] += a * r2s[ti];
                    nsq += m[rl][ti] * m[rl][ti];
                }
            }
            for (int mk = 1; mk < 64; mk <<= 1) nsq += __shfl_xor(nsq, mk, 64);
            __syncthreads();
            if ((tid & 63) == 0) wred[tid >> 6] = nsq;
            __syncthreads();
            float nrm = sqrtf(wred[0] + wred[1] + wred[2] + wred[3]);
            float sc = nrm > 1.0f ? 1.0f / nrm : 1.0f;   // relu(nrm-1)+1 == max(nrm,1)
            float rp = 0.f;
#pragma unroll
            for (int rl = 0; rl < 4; rl++) {
                float s = 0.f;
                for (int ti = 0; ti < 32; ti++) {
                    m[rl][ti] *= sc;
                    s += m[rl][ti] * u2s[ti];
                }
                rp += u1s[rg * 4 + rl] * s;
            }
            red[rg][f] = rp;
            __syncthreads();
            float rv = 0.f;
#pragma unroll
            for (int g = 0; g < 8; g++) rv += red[g][f];
            float mean = rv;
            for (int mk = 1; mk < 32; mk <<= 1) mean += __shfl_xor(mean, mk, 32);
            mean *= (1.0f / 32.0f);
            float d = rv - mean;
            float var = d * d;
            for (int mk = 1; mk < 32; mk <<= 1) var += __shfl_xor(var, mk, 32);
            var *= (1.0f / 32.0f);
            if (tid < 32) {
                float y = d * rsqrtf(var + 1e-5f);
                llc_store_u16(acat + ((size_t)t * 64 + sb) * 544 + 512 + f, f2bf(y));
            }
            __syncthreads();
        }
    } else {
        // =================== persistent slot workers (blk 192..254) =======
        const int wid = blk - 192;   // 0..62
        stage_slot_weights(sm.s, tid, Wq, bq, Wk, bk, Wv, bv, lng, lnb,
                           Wm1, bm1, Wm2, bm2, Wsp, bsp);
        __syncthreads();
        int* myprog = prog + wid * 16;
        for (int u = wid; u < 8192; u += 63) {
            const int t = u >> 4, s = u & 15;
            if (s < 8)
                slot_unit<3>(sm.s, tid, (size_t)t * 64 + s * 8, dec, initb, r1, r2, fi);
            else
                slot_unit<2>(sm.s, tid, (size_t)t * 64 + (s - 8) * 8, dec, initr, uu1, uu2, nullptr);
            __builtin_amdgcn_s_waitcnt(0);   // this thread's output stores acked
            __syncthreads();                 // all threads drained; LDS reusable
            if (tid == 0) ag_store(myprog, u + 63);   // no pending unit < u+63
        }
    }
}

// ---------------------------------------------------------------------------
extern "C" void kernel_launch(void* const* d_in, const int* in_sizes, int n_in,
                              void* d_out, int out_size, void* d_ws, size_t ws_size,
                              hipStream_t stream)
{
    (void)in_sizes; (void)n_in; (void)out_size; (void)ws_size;
    const int*   tokens = (const int*)d_in[0];
    const float* embW  = (const float*)d_in[1];
    const float* Wih0  = (const float*)d_in[2];
    const float* Whh0  = (const float*)d_in[3];
    const float* bih0  = (const float*)d_in[4];
    const float* bhh0  = (const float*)d_in[5];
    const float* Wih1  = (const float*)d_in[6];
    const float* Whh1  = (const float*)d_in[7];
    const float* bih1  = (const float*)d_in[8];
    const float* bhh1  = (const float*)d_in[9];
    const float* Wpi   = (const float*)d_in[10];
    const float* bpi   = (const float*)d_in[11];
    const float* Wq    = (const float*)d_in[12];
    const float* bq    = (const float*)d_in[13];
    const float* Wk    = (const float*)d_in[14];
    const float* bk    = (const float*)d_in[15];
    const float* Wv    = (const float*)d_in[16];
    const float* bv    = (const float*)d_in[17];
    const float* lng   = (const float*)d_in[18];
    const float* lnb   = (const float*)d_in[19];
    const float* Wm1   = (const float*)d_in[20];
    const float* bm1   = (const float*)d_in[21];
    const float* Wm2   = (const float*)d_in[22];
    const float* bm2   = (const float*)d_in[23];
    const float* Wbind = (const float*)d_in[24];
    const float* bbind = (const float*)d_in[25];
    const float* Wreas = (const float*)d_in[26];
    const float* breas = (const float*)d_in[27];
    const float* Wsp   = (const float*)d_in[28];
    const float* bsp   = (const float*)d_in[29];
    const float* Wg    = (const float*)d_in[30];
    const float* bg    = (const float*)d_in[31];
    const float* Wout  = (const float*)d_in[32];
    const float* bout  = (const float*)d_in[33];

    char* ws = (char*)d_ws;
    size_t off = 0;
    auto alloc = [&](size_t bytes) { size_t o = off; off += (bytes + 255) & ~(size_t)255; return o; };
    int*  flags  = (int*)(ws + alloc(16384 * 4));   // f0, f1, f1s, prog
    u16*  emb    = (u16*)(ws + alloc(32768ull * 256 * 2));
    u16*  dec    = (u16*)(ws + alloc(32768ull * 192 * 2));
    u16*  initb  = (u16*)(ws + alloc(32768ull * 96 * 2));
    u16*  initr  = (u16*)(ws + alloc(32768ull * 64 * 2));
    u16*  acat   = (u16*)(ws + alloc(32768ull * 544 * 2));
    u16*  h0seq  = (u16*)(ws + alloc(512ull * 64 * 512 * 2));
    u16*  h1seq  = (u16*)(ws + alloc(512ull * 64 * 512 * 2));
    float* role1 = (float*)(ws + alloc(32768ull * 32 * 4));
    float* role2 = (float*)(ws + alloc(32768ull * 32 * 4));
    float* fill  = (float*)(ws + alloc(32768ull * 32 * 4));
    float* u1v   = (float*)(ws + alloc(32768ull * 32 * 4));
    float* u2v   = (float*)(ws + alloc(32768ull * 32 * 4));
    u16* Wx0b  = (u16*)(ws + alloc(2048ull * 256 * 2));
    u16* Wh0b  = (u16*)(ws + alloc(2048ull * 512 * 2));
    u16* Wx1b  = (u16*)(ws + alloc(2048ull * 512 * 2));
    u16* Wh1b  = (u16*)(ws + alloc(2048ull * 512 * 2));
    u16* Wpib  = (u16*)(ws + alloc(192ull * 256 * 2));
    u16* Wbindb = (u16*)(ws + alloc(96ull * 192 * 2));
    u16* Wreasb = (u16*)(ws + alloc(64ull * 192 * 2));
    u16* Woutb  = (u16*)(ws + alloc(128ull * 544 * 2));

    hipMemsetAsync(flags, 0, 16384 * 4, stream);
    {
        Cvt8 c;
        const float* s[8] = {Wih0, Whh0, Wih1, Whh1, Wpi, Wbind, Wreas, Wout};
        u16* d[8] = {Wx0b, Wh0b, Wx1b, Wh1b, Wpib, Wbindb, Wreasb, Woutb};
        int n[8] = {2048 * 256, 2048 * 512, 2048 * 512, 2048 * 512,
                    192 * 256, 96 * 192, 64 * 192, 128 * 544};
        int acc = 0;
        for (int k = 0; k < 8; k++) { c.s[k] = s[k]; c.d[k] = d[k]; c.off4[k] = acc; acc += n[k] / 4; }
        c.off4[8] = acc;
        k_f2b8<<<(acc + 255) / 256, 256, 0, stream>>>(c);
    }
    k_embed<<<4096, 256, 0, stream>>>(tokens, embW, emb);
    k_gemm_bt<<<dim3(256, 2), 256, 0, stream>>>(emb, 256, Wpib, dec, nullptr, 192, bpi, nullptr, 192, 256);
    k_gemm_bt<<<dim3(256, 1), 256, 0, stream>>>(dec, 192, Wbindb, initb, nullptr, 96, bbind, nullptr, 96, 192);
    k_gemm_bt<<<dim3(256, 1), 256, 0, stream>>>(dec, 192, Wreasb, initr, nullptr, 64, breas, nullptr, 64, 192);
    // fused: LSTM(2 layers) + scan/gate + BOTH slot passes (CU-partitioned)
    k_mega<<<255, 256, 0, stream>>>(emb, Wx0b, Wh0b, Wx1b, Wh1b,
                                    bih0, bhh0, bih1, bhh1,
                                    h0seq, h1seq, acat, flags,
                                    role1, role2, fill, u1v, u2v, Wg, bg,
                                    dec, initb, initr,
                                    Wq, bq, Wk, bk, Wv, bv, lng, lnb,
                                    Wm1, bm1, Wm2, bm2, Wsp, bsp);
    // out = acat @ Wout^T + bout  (fp32 output)
    k_gemm_bt<<<dim3(256, 1), 256, 0, stream>>>(acat, 544, Woutb, nullptr, (float*)d_out, 128, bout, nullptr, 128, 544);
}

// Round 16
// 3225.621 us; speedup vs baseline: 1.5533x; 1.0157x over previous
//
#include <hip/hip_runtime.h>

typedef unsigned short u16;
typedef unsigned int u32;
typedef unsigned long long u64;
typedef __bf16 bf16x8 __attribute__((ext_vector_type(8)));
typedef float f32x4 __attribute__((ext_vector_type(4)));

__device__ __forceinline__ float bf2f(u16 u) { return __uint_as_float(((u32)u) << 16); }
__device__ __forceinline__ u16 f2bf(float f) {
    u32 u = __float_as_uint(f);
    u32 r = (u + 0x7FFFu + ((u >> 16) & 1u)) >> 16;
    return (u16)r;
}
__device__ __forceinline__ float sigm(float x) { return 1.0f / (1.0f + __expf(-x)); }
__device__ __forceinline__ float elu1(float x) { return x > 0.0f ? x + 1.0f : __expf(x); }

// agent-scope (LLC) atomics — HW-validated cross-XCD path (R5/R7)
__device__ __forceinline__ int ag_load(const int* p) {
    return __hip_atomic_load(p, __ATOMIC_RELAXED, __HIP_MEMORY_SCOPE_AGENT);
}
__device__ __forceinline__ void ag_store(int* p, int v) {
    __hip_atomic_store(p, v, __ATOMIC_RELAXED, __HIP_MEMORY_SCOPE_AGENT);
}
__device__ __forceinline__ void ag_storef(float* p, float v) {
    __hip_atomic_store(p, v, __ATOMIC_RELAXED, __HIP_MEMORY_SCOPE_AGENT);
}
__device__ __forceinline__ void llc_store2(u16* p, u16 a, u16 b) {
    u32 v = (u32)a | ((u32)b << 16);
    __hip_atomic_store((u32*)p, v, __ATOMIC_RELAXED, __HIP_MEMORY_SCOPE_AGENT);
}
__device__ __forceinline__ void llc_store_u16(u16* p, u16 v) {
    __hip_atomic_store(p, v, __ATOMIC_RELAXED, __HIP_MEMORY_SCOPE_AGENT);
}

// ---------------------------------------------------------------------------
struct Cvt8 { const float* s[8]; u16* d[8]; int off4[9]; };

__global__ __launch_bounds__(256) void k_f2b8(Cvt8 c)
{
    int i = blockIdx.x * 256 + threadIdx.x;
    if (i >= c.off4[8]) return;
    int k = 0;
#pragma unroll
    for (int q = 1; q < 8; q++) if (i >= c.off4[q]) k = q;
    int j = i - c.off4[k];
    float4 v = ((const float4*)c.s[k])[j];
    ushort4 o;
    o.x = f2bf(v.x); o.y = f2bf(v.y); o.z = f2bf(v.z); o.w = f2bf(v.w);
    ((ushort4*)c.d[k])[j] = o;
}

// ---------------------------------------------------------------------------
__global__ __launch_bounds__(256) void k_embed(const int* __restrict__ tok,
                                               const float* __restrict__ W,
                                               u16* __restrict__ out)
{
    int c = blockIdx.x * 256 + threadIdx.x;
    int row = c >> 5, cc = (c & 31) * 8;
    int t = tok[row];
    const float* src = W + (size_t)t * 256 + cc;
    u16 tmp[8];
#pragma unroll
    for (int k = 0; k < 8; k++) tmp[k] = f2bf(src[k]);
    *(uint4*)(out + (size_t)row * 256 + cc) = *(uint4*)tmp;
}

// ---------------------------------------------------------------------------
// GEMM:  C[M,N] = A[M,K](bf16, lda) * B[N,K]^T(bf16) + bias. 128x128 tile.
// ---------------------------------------------------------------------------
__global__ __launch_bounds__(256) void k_gemm_bt(
    const u16* __restrict__ A, int lda,
    const u16* __restrict__ B,
    u16* __restrict__ Cb, float* __restrict__ Cf, int ldc,
    const float* __restrict__ bias1, const float* __restrict__ bias2,
    int N, int K)
{
    __shared__ u16 As[128][40];
    __shared__ u16 Bs[128][40];
    const int tid = threadIdx.x;
    const int m0 = blockIdx.x * 128, n0 = blockIdx.y * 128;
    const int wave = tid >> 6, lane = tid & 63;
    const int wm = wave & 1, wn = wave >> 1;
    const int quad = lane >> 4, l16 = lane & 15;
    f32x4 acc[4][4] = {};
    for (int k0 = 0; k0 < K; k0 += 32) {
        __syncthreads();
#pragma unroll
        for (int i = 0; i < 2; i++) {
            int c = tid + i * 256, row = c >> 2, cc = (c & 3) * 8;
            *(uint4*)(&As[row][cc]) = *(const uint4*)(A + (size_t)(m0 + row) * lda + k0 + cc);
            uint4 d = {0, 0, 0, 0};
            if (n0 + row < N) d = *(const uint4*)(B + (size_t)(n0 + row) * K + k0 + cc);
            *(uint4*)(&Bs[row][cc]) = d;
        }
        __syncthreads();
        bf16x8 af[4], bfm[4];
#pragma unroll
        for (int x = 0; x < 4; x++) {
            af[x]  = *(const bf16x8*)(&As[wm * 64 + x * 16 + l16][quad * 8]);
            bfm[x] = *(const bf16x8*)(&Bs[wn * 64 + x * 16 + l16][quad * 8]);
        }
#pragma unroll
        for (int mi = 0; mi < 4; mi++)
#pragma unroll
            for (int ni = 0; ni < 4; ni++)
                acc[mi][ni] = __builtin_amdgcn_mfma_f32_16x16x32_bf16(af[mi], bfm[ni], acc[mi][ni], 0, 0, 0);
    }
#pragma unroll
    for (int ni = 0; ni < 4; ni++) {
        int col = n0 + wn * 64 + ni * 16 + l16;
        if (col < N) {
            float bv = 0.f;
            if (bias1) bv += bias1[col];
            if (bias2) bv += bias2[col];
#pragma unroll
            for (int mi = 0; mi < 4; mi++) {
                int r0 = m0 + wm * 64 + mi * 16 + quad * 4;
#pragma unroll
                for (int r = 0; r < 4; r++) {
                    float v = acc[mi][ni][r] + bv;
                    if (Cb) Cb[(size_t)(r0 + r) * ldc + col] = f2bf(v);
                    else    Cf[(size_t)(r0 + r) * ldc + col] = v;
                }
            }
        }
    }
}

// ---------------------------------------------------------------------------
// Shared-memory union: one kernel, three block roles (LSTM / scan / slot).
// ---------------------------------------------------------------------------
struct SmemLstm {
    u16 Wx[32][528];
    u16 Wh[32][528];
    float zs[4][16][33];
};
struct SmemSlot {
    float WqT[32][33], WkT[64][33], WvT[64][33], Wm1T[32][65], Wm2T[64][33], WspT[64][33];
    float bq[32], bk[32], bv[32], bm1[64], bm2[32], bsp[32], g[32], be[32];
    u16 xbuf[8][192];
    float slots[8][3][32], initl[8][3][32], kk[8][3][32], vv[8][3][32], qq[8][3][32];
    float att[8][3][4];
    float ubuf[8][32];
    float hid[8][64];
};
struct SmemScan {
    float r1s[32], r2s[32], fis[32], u1s[32], u2s[32];
    float red[8][32];
    float wred[4];
    float gpart[4];
};
union SmemU {
    SmemLstm l;
    SmemSlot s;
    SmemScan c;
};

// ---------------------------------------------------------------------------
// Slot attention — weights staged once per worker. R23 (= R22 resubmitted
// after an infra-level container failure; all poll loops are bounded and the
// progress invariant is verified, so a kernel-induced crash is implausible):
// bind unit (t,s) and reas unit (t,s-8) read the SAME 8 dec rows and compute
// the SAME k/v projections (identical inputs & weights; only init-slots
// differ). Merged unit: xbuf + kk/vv once, then pass A (NSLOT=3, bind) and
// pass B (NSLOT=2, reas) reuse them. Work ELIMINATION (~18%/pair), not
// rescheduling. kk/vv/xbuf are never written by the iteration phases.
// ---------------------------------------------------------------------------
__device__ __forceinline__ void stage_slot_weights(SmemSlot& S, const int tid,
    const float* __restrict__ Wq, const float* __restrict__ bq,
    const float* __restrict__ Wk, const float* __restrict__ bk,
    const float* __restrict__ Wv, const float* __restrict__ bv,
    const float* __restrict__ lng, const float* __restrict__ lnb,
    const float* __restrict__ Wm1, const float* __restrict__ bm1,
    const float* __restrict__ Wm2, const float* __restrict__ bm2,
    const float* __restrict__ Wsp, const float* __restrict__ bsp)
{
    for (int i = tid; i < 1024; i += 256) { int o = i >> 5, c = i & 31; S.WqT[c][o] = Wq[o * 32 + c]; }
    for (int i = tid; i < 2048; i += 256) {
        int o6 = i >> 6, c6 = i & 63;
        S.WkT[c6][o6]  = Wk[o6 * 64 + c6];
        S.WvT[c6][o6]  = Wv[o6 * 64 + c6];
        S.Wm2T[c6][o6] = Wm2[o6 * 64 + c6];
        S.WspT[c6][o6] = Wsp[o6 * 64 + c6];
        int o5 = i >> 5, c5 = i & 31;
        S.Wm1T[c5][o5] = Wm1[o5 * 32 + c5];
    }
    if (tid < 32) {
        S.bq[tid] = bq[tid]; S.bk[tid] = bk[tid]; S.bv[tid] = bv[tid];
        S.bm2[tid] = bm2[tid]; S.bsp[tid] = bsp[tid];
        S.g[tid] = lng[tid]; S.be[tid] = lnb[tid];
    }
    if (tid < 64) S.bm1[tid] = bm1[tid];
}

// Shared phase: xbuf load + k/v projection (identical for bind and reas).
__device__ __forceinline__ void slot_kv(SmemSlot& S, const int tid,
                                        const size_t row0,
                                        const u16* __restrict__ dec)
{
    const int p = tid >> 5, l = tid & 31;
    const size_t row = row0 + p;
    for (int i = l; i < 192; i += 32) S.xbuf[p][i] = dec[row * 192 + i];
    __syncthreads();
#pragma unroll
    for (int i = 0; i < 3; i++) {
        float aK = S.bk[l], aV = S.bv[l];
        for (int c = 0; c < 64; c++) {
            float x = bf2f(S.xbuf[p][i * 64 + c]);
            aK += x * S.WkT[c][l];
            aV += x * S.WvT[c][l];
        }
        S.kk[p][i][l] = elu1(aK);
        S.vv[p][i][l] = aV;
    }
    // no barrier here: slot_pass stages initl then barriers, covering kk/vv
    // writes exactly as the champion's single-unit ordering did.
}

template <int NSLOT>
__device__ __forceinline__ void slot_pass(
    SmemSlot& S, const int tid, const size_t row0,
    const u16* __restrict__ initp,
    float* __restrict__ o1, float* __restrict__ o2, float* __restrict__ o3)
{
    const int p = tid >> 5, l = tid & 31;
    const size_t row = row0 + p;
#pragma unroll
    for (int j = 0; j < NSLOT; j++) {
        float iv = bf2f(initp[row * (NSLOT * 32) + j * 32 + l]);
        S.initl[p][j][l] = iv;
        S.slots[p][j][l] = iv;
    }
    __syncthreads();
    const float rs = 0.17677669529663687f;
    for (int it = 0; it < 3; it++) {
#pragma unroll
        for (int j = 0; j < NSLOT; j++) {
            float a = S.bq[l];
            for (int c = 0; c < 32; c++) a += S.slots[p][j][c] * S.WqT[c][l];
            S.qq[p][j][l] = elu1((a + S.initl[p][j][l]) * rs);
        }
        __syncthreads();
        if (l < 3 * NSLOT) {
            int i = l / NSLOT, j = l % NSLOT;
            float s = 0.f;
            for (int c = 0; c < 32; c++) s += S.kk[p][i][c] * S.qq[p][j][c];
            S.att[p][i][j] = s;
        }
        __syncthreads();
        if (l < 3) {
            float mx = -1e30f;
            for (int j = 0; j < NSLOT; j++) mx = fmaxf(mx, S.att[p][l][j]);
            float sm = 0.f, ex[3];
            for (int j = 0; j < NSLOT; j++) { ex[j] = __expf(S.att[p][l][j] - mx); sm += ex[j]; }
            for (int j = 0; j < NSLOT; j++) S.att[p][l][j] = ex[j] / sm + 1e-8f;
        }
        __syncthreads();
        if (l < NSLOT) {
            float s = S.att[p][0][l] + S.att[p][1][l] + S.att[p][2][l];
            float inv = 1.0f / s;
            for (int i = 0; i < 3; i++) S.att[p][i][l] *= inv;
        }
        __syncthreads();
#pragma unroll
        for (int j = 0; j < NSLOT; j++) {
            float u = S.att[p][0][j] * S.vv[p][0][l] + S.att[p][1][j] * S.vv[p][1][l] + S.att[p][2][j] * S.vv[p][2][l];
            float mean = u;
            for (int mk = 1; mk < 32; mk <<= 1) mean += __shfl_xor(mean, mk, 32);
            mean *= (1.0f / 32.0f);
            float d = u - mean;
            float var = d * d;
            for (int mk = 1; mk < 32; mk <<= 1) var += __shfl_xor(var, mk, 32);
            var *= (1.0f / 32.0f);
            float y = d * rsqrtf(var + 1e-5f) * S.g[l] + S.be[l];
            S.ubuf[p][l] = y;
            __syncthreads();
#pragma unroll
            for (int oo = 0; oo < 2; oo++) {
                int o = l + oo * 32;
                float a = S.bm1[o];
                for (int c = 0; c < 32; c++) a += S.ubuf[p][c] * S.Wm1T[c][o];
                S.hid[p][o] = fmaxf(a, 0.f);
            }
            __syncthreads();
            float a2 = S.bm2[l];
            for (int c = 0; c < 64; c++) a2 += S.hid[p][c] * S.Wm2T[c][l];
            S.slots[p][j][l] += a2 * (1.0f / 32.0f);
            __syncthreads();
        }
    }
    float pj[NSLOT];
#pragma unroll
    for (int j = 0; j < NSLOT; j++) {
        float a = S.bsp[l];
        for (int c = 0; c < 32; c++) a += S.initl[p][j][c] * S.WspT[c][l];
        for (int c = 0; c < 32; c++) a += S.slots[p][j][c] * S.WspT[32 + c][l];
        pj[j] = a;
    }
    const float e = 1e-6f, me = (float)(1.0 - 2e-6);
    if (NSLOT == 3) {
        ag_storef(&o1[row * 32 + l], tanhf(me * pj[0] + e * pj[1] + e * pj[2]));
        ag_storef(&o2[row * 32 + l], tanhf(e * pj[0] + me * pj[1] + e * pj[2]));
        ag_storef(&o3[row * 32 + l], tanhf(e * pj[0] + e * pj[1] + me * pj[2]));
    } else {
        ag_storef(&o1[row * 32 + l], tanhf(me * pj[0] + e * pj[1]));
        ag_storef(&o2[row * 32 + l], tanhf(e * pj[0] + me * pj[1]));
    }
}

// ---------------------------------------------------------------------------
// Mega kernel, 255 blocks (~1 per CU — CU-PARTITIONED roles):
//   0..127   wave-autonomous LSTM (R10 champion verbatim)
//   128..191 trailing scan + gate (dual gate; slot chunk = 8 MERGED units)
//   192..254 63 persistent slot workers sweeping 4096 MERGED units (m%63,
//            t = m>>3): shared kv phase + bind pass + reas pass.
// Worker k publishes p[k] = m+63 on its own line; chunk t ready <=>
// min_k p[k] >= (t+1)*8. (Worker k's final publish >= 4096 = need(511),
// so the gate always releases — no hang path; all polls bounded.)
//   flags: f0 @0, f1 @4096, f1s @8192, prog @12288 (63 x stride-16)
// ---------------------------------------------------------------------------
__global__ __launch_bounds__(256) void k_mega(
    const u16* __restrict__ emb,
    const u16* __restrict__ Wx0, const u16* __restrict__ Wh0,
    const u16* __restrict__ Wx1, const u16* __restrict__ Wh1,
    const float* __restrict__ bi0, const float* __restrict__ bh0,
    const float* __restrict__ bi1, const float* __restrict__ bh1,
    u16* __restrict__ h0seq,        // [512][64][64][8] block-major
    u16* __restrict__ h1seq,        // [512][64][64][8] block-major
    u16* __restrict__ acat,         // [32768][544]; cols 0..511 h1, 512.. scan out
    int* __restrict__ flags,
    float* __restrict__ r1, float* __restrict__ r2,
    float* __restrict__ fi, float* __restrict__ uu1, float* __restrict__ uu2,
    const float* __restrict__ Wg, const float* __restrict__ bg,
    const u16* __restrict__ dec,
    const u16* __restrict__ initb, const u16* __restrict__ initr,
    const float* __restrict__ Wq, const float* __restrict__ bq,
    const float* __restrict__ Wk, const float* __restrict__ bk,
    const float* __restrict__ Wv, const float* __restrict__ bv,
    const float* __restrict__ lng, const float* __restrict__ lnb,
    const float* __restrict__ Wm1, const float* __restrict__ bm1,
    const float* __restrict__ Wm2, const float* __restrict__ bm2,
    const float* __restrict__ Wsp, const float* __restrict__ bsp)
{
    __shared__ SmemU sm;
    const int tid = threadIdx.x;
    const int blk = blockIdx.x;
    int* f0   = flags;
    int* f1   = flags + 4096;
    int* f1s  = flags + 8192;
    int* prog = flags + 12288;

    if (blk < 128) {
        // =================== wave-autonomous LSTM (R10 verbatim) ==========
        auto& Wx = sm.l.Wx;
        auto& Wh = sm.l.Wh;
        auto& zs = sm.l.zs;
        const int layer = blk >> 6;
        const int me = blk & 63;
        const int jbase = me * 8;
        const int Kx = layer ? 512 : 256;
        const u16* Wxp = layer ? Wx1 : Wx0;
        const u16* Whp = layer ? Wh1 : Wh0;
        const float* bi = layer ? bi1 : bi0;
        const float* bh = layer ? bh1 : bh0;
#pragma unroll
        for (int i = 0; i < 8; i++) {
            int c = tid + i * 256;
            int row = c >> 6, cc = (c & 63) * 8;
            int grow = (row >> 3) * 512 + jbase + (row & 7);
            *(uint4*)(&Wh[row][cc]) = *(const uint4*)(Whp + (size_t)grow * 512 + cc);
        }
        {
            int cpr = Kx >> 3;
            int iters = (32 * cpr) >> 8;
            for (int i = 0; i < iters; i++) {
                int c = tid + i * 256;
                int row = c / cpr, cc = (c % cpr) * 8;
                int grow = (row >> 3) * 512 + jbase + (row & 7);
                *(uint4*)(&Wx[row][cc]) = *(const uint4*)(Wxp + (size_t)grow * Kx + cc);
            }
        }
        const int wave = tid >> 6, lane = tid & 63;
        const int quad = lane >> 4, l16 = lane & 15;
        const int m = wave * 16 + l16;       // global batch row for MFMA A-load
        const int bl = lane >> 2;            // local batch (0..15)
        const int b = wave * 16 + bl;        // global batch for elementwise
        const int jj = (lane & 3) * 2;       // local col pair
        const int hoff = quad * 512 + m * 8; // block-major read offset (elements)
        float bia0[4], bia1[4];
#pragma unroll
        for (int g = 0; g < 4; g++) {
            bia0[g] = bi[g * 512 + jbase + jj]     + bh[g * 512 + jbase + jj];
            bia1[g] = bi[g * 512 + jbase + jj + 1] + bh[g * 512 + jbase + jj + 1];
        }
        const int pollOwn = (wave * 64 + lane) * 16;   // lane polls block `lane`, group `wave`
        const int pubIdx  = (wave * 64 + me) * 16;
        float c0 = 0.f, c1 = 0.f;
        __syncthreads();   // Wx/Wh staged; last barrier before the loop
        for (int t = 0; t < 512; t++) {
            f32x4 acc0 = {}, acc1 = {};
            if (!layer) {
                // x-part (emb, independent of flags)
                const u16* xrow = emb + ((size_t)t * 64 + m) * 256;
#pragma unroll
                for (int kc = 0; kc < 8; kc++) {
                    bf16x8 a  = *(const bf16x8*)(xrow + kc * 32 + quad * 8);
                    bf16x8 w0 = *(const bf16x8*)(&Wx[l16][kc * 32 + quad * 8]);
                    bf16x8 w1 = *(const bf16x8*)(&Wx[16 + l16][kc * 32 + quad * 8]);
                    acc0 = __builtin_amdgcn_mfma_f32_16x16x32_bf16(a, w0, acc0, 0, 0, 0);
                    acc1 = __builtin_amdgcn_mfma_f32_16x16x32_bf16(a, w1, acc1, 0, 0, 0);
                }
                if (t > 0) {   // wait for group-w h0[t-1]
                    int it = 0;
                    for (;;) {
                        int a = ag_load(f0 + pollOwn);
                        if (__all(a >= t)) break;
                        if (++it > 3000000) break;
                        __builtin_amdgcn_s_sleep(1);
                    }
                    const u16* hrd = h0seq + (size_t)(t - 1) * 32768 + hoff;
#pragma unroll
                    for (int kc = 0; kc < 16; kc++) {
                        bf16x8 a  = *(const bf16x8*)(hrd + kc * 2048);
                        bf16x8 w0 = *(const bf16x8*)(&Wh[l16][kc * 32 + quad * 8]);
                        bf16x8 w1 = *(const bf16x8*)(&Wh[16 + l16][kc * 32 + quad * 8]);
                        acc0 = __builtin_amdgcn_mfma_f32_16x16x32_bf16(a, w0, acc0, 0, 0, 0);
                        acc1 = __builtin_amdgcn_mfma_f32_16x16x32_bf16(a, w1, acc1, 0, 0, 0);
                    }
                }
            } else {
                // wait for h0[t] (f0 group w >= t+1), then x-part
                {
                    int it = 0;
                    for (;;) {
                        int a = ag_load(f0 + pollOwn);
                        if (__all(a >= t + 1)) break;
                        if (++it > 3000000) break;
                        __builtin_amdgcn_s_sleep(1);
                    }
                }
                const u16* xrow = h0seq + (size_t)t * 32768 + hoff;
#pragma unroll
                for (int kc = 0; kc < 16; kc++) {
                    bf16x8 a  = *(const bf16x8*)(xrow + kc * 2048);
                    bf16x8 w0 = *(const bf16x8*)(&Wx[l16][kc * 32 + quad * 8]);
                    bf16x8 w1 = *(const bf16x8*)(&Wx[16 + l16][kc * 32 + quad * 8]);
                    acc0 = __builtin_amdgcn_mfma_f32_16x16x32_bf16(a, w0, acc0, 0, 0, 0);
                    acc1 = __builtin_amdgcn_mfma_f32_16x16x32_bf16(a, w1, acc1, 0, 0, 0);
                }
                if (t > 0) {   // wait for group-w h1[t-1], then h-part
                    int it = 0;
                    for (;;) {
                        int a = ag_load(f1 + pollOwn);
                        if (__all(a >= t)) break;
                        if (++it > 3000000) break;
                        __builtin_amdgcn_s_sleep(1);
                    }
                    const u16* hrd = h1seq + (size_t)(t - 1) * 32768 + hoff;
#pragma unroll
                    for (int kc = 0; kc < 16; kc++) {
                        bf16x8 a  = *(const bf16x8*)(hrd + kc * 2048);
                        bf16x8 w0 = *(const bf16x8*)(&Wh[l16][kc * 32 + quad * 8]);
                        bf16x8 w1 = *(const bf16x8*)(&Wh[16 + l16][kc * 32 + quad * 8]);
                        acc0 = __builtin_amdgcn_mfma_f32_16x16x32_bf16(a, w0, acc0, 0, 0, 0);
                        acc1 = __builtin_amdgcn_mfma_f32_16x16x32_bf16(a, w1, acc1, 0, 0, 0);
                    }
                }
            }
            // wave-local z staging (no barrier: same-wave LDS, lgkmcnt only)
#pragma unroll
            for (int r = 0; r < 4; r++) {
                zs[wave][quad * 4 + r][l16]      = acc0[r];
                zs[wave][quad * 4 + r][16 + l16] = acc1[r];
            }
            u16 hb0, hb1;
            {
                float zi0 = zs[wave][bl][jj]      + bia0[0];
                float zf0 = zs[wave][bl][8 + jj]  + bia0[1];
                float zg0 = zs[wave][bl][16 + jj] + bia0[2];
                float zo0 = zs[wave][bl][24 + jj] + bia0[3];
                c0 = sigm(zf0) * c0 + sigm(zi0) * tanhf(zg0);
                float h0v = sigm(zo0) * tanhf(c0);
                float zi1 = zs[wave][bl][jj + 1]      + bia1[0];
                float zf1 = zs[wave][bl][8 + jj + 1]  + bia1[1];
                float zg1 = zs[wave][bl][16 + jj + 1] + bia1[2];
                float zo1 = zs[wave][bl][24 + jj + 1] + bia1[3];
                c1 = sigm(zf1) * c1 + sigm(zi1) * tanhf(zg1);
                float h1v = sigm(zo1) * tanhf(c1);
                hb0 = f2bf(h0v); hb1 = f2bf(h1v);
            }
            if (!layer) {
                // block-major contiguous store: wave writes 256 B (4 full lines)
                llc_store2(h0seq + (size_t)t * 32768 + me * 512 + b * 8 + jj, hb0, hb1);
                __builtin_amdgcn_s_waitcnt(0);
                if (lane == 0) ag_store(f0 + pubIdx, t + 1);
            } else {
                llc_store2(h1seq + (size_t)t * 32768 + me * 512 + b * 8 + jj, hb0, hb1);
                __builtin_amdgcn_s_waitcnt(0);   // drain recurrence copy only
                if (lane == 0) ag_store(f1 + pubIdx, t + 1);
                // row-major copy for scan gate + final GEMM (off critical path)
                llc_store2(acat + ((size_t)t * 64 + b) * 544 + jbase + jj, hb0, hb1);
                __builtin_amdgcn_s_waitcnt(0);
                if (lane == 0) ag_store(f1s + pubIdx, t + 1);
            }
        }
    } else if (blk < 192) {
        // =================== trailing scan + inline gate ==================
        const int sb = blk - 128;          // batch
        const int grp = sb >> 4;           // its batch group
        const int f = tid & 31, rg = tid >> 5;
        float m[4][32];
#pragma unroll
        for (int x = 0; x < 4; x++)
            for (int y = 0; y < 32; y++) m[x][y] = 0.f;
        auto& r1s = sm.c.r1s;
        auto& r2s = sm.c.r2s;
        auto& fis = sm.c.fis;
        auto& u1s = sm.c.u1s;
        auto& u2s = sm.c.u2s;
        auto& red = sm.c.red;
        auto& wred = sm.c.wred;
        auto& gpart = sm.c.gpart;
        float wg0 = Wg[2 * tid], wg1 = Wg[2 * tid + 1];
        float bgv = bg[0];
        for (int t = 0; t < 512; t++) {
            // dual gate: wave0 polls LSTM f1s; wave1 polls slot worker progress
            // (chunk t ready <=> all MERGED units < (t+1)*8 done)
            if (tid < 64) {
                int* p1 = f1s + (grp * 64 + tid) * 16;
                int it = 0;
                for (;;) {
                    int a = ag_load(p1);
                    if (__all(a >= t + 1)) break;
                    if (++it > 3000000) break;
                    __builtin_amdgcn_s_sleep(1);
                }
            } else if (tid < 128) {
                const int k = tid - 64;
                const int* pp = prog + k * 16;
                const int need = (t + 1) * 8;
                int it = 0;
                for (;;) {
                    int a = 0x7FFFFFFF;
                    if (k < 63) a = ag_load(pp);
                    if (__all(a >= need)) break;
                    if (++it > 3000000) break;
                    __builtin_amdgcn_s_sleep(1);
                }
            }
            __syncthreads();
            // preloads AFTER the gates (slot outputs are produced concurrently)
            float pre = 0.f;
            {
                size_t base = ((size_t)t * 64 + sb) * 32;
                if (tid < 32) pre = r1[base + tid];
                else if (tid < 64) pre = r2[base + tid - 32];
                else if (tid < 96) pre = fi[base + tid - 64];
                else if (tid < 128) pre = uu1[base + tid - 96];
                else if (tid < 160) pre = uu2[base + tid - 128];
            }
            {
                const u16* hr = acat + ((size_t)t * 64 + sb) * 544;
                u32 hv = *(const u32*)(hr + 2 * tid);
                float gp = bf2f((u16)hv) * wg0 + bf2f((u16)(hv >> 16)) * wg1;
                for (int mk = 1; mk < 64; mk <<= 1) gp += __shfl_xor(gp, mk, 64);
                if ((tid & 63) == 0) gpart[tid >> 6] = gp;
            }
            if (tid < 32) r1s[tid] = pre;
            else if (tid < 64) r2s[tid - 32] = pre;
            else if (tid < 96) fis[tid - 64] = pre;
            else if (tid < 128) u1s[tid - 96] = pre;
            else if (tid < 160) u2s[tid - 128] = pre;
            __syncthreads();
            float gsh = sigm(gpart[0] + gpart[1] + gpart[2] + gpart[3] + bgv + 1.0f);
            float p = 0.f;
#pragma unroll
            for (int rl = 0; rl < 4; rl++) {
                float s = 0.f;
                for (int ti = 0; ti < 32; ti++) s += r2s[ti] * m[rl][ti];
                p += r1s[rg * 4 + rl] * s;
            }
            red[rg][f] = p;
            __syncthreads();
            float prev = 0.f;
#pragma unroll
            for (int g = 0; g < 8; g++) prev += red[g][f];
            float curo = gsh * (fis[f] - prev) * (1.0f / 32.0f);
            float nsq = 0.f;
#pragma unroll
            for (int rl = 0; rl < 4; rl++) {
                float a = r1s[rg * 4 + rl] * curo;
                for (int ti = 0; ti < 32; ti++) {
                    m[rl][ti] += a * r2s[ti];
                    nsq += m[rl][ti] * m[rl][ti];
                }
            }
            for (int mk = 1; mk < 64; mk <<= 1) nsq += __shfl_xor(nsq, mk, 64);
            __syncthreads();
            if ((tid & 63) == 0) wred[tid >> 6] = nsq;
            __syncthreads();
            float nrm = sqrtf(wred[0] + wred[1] + wred[2] + wred[3]);
            float sc = nrm > 1.0f ? 1.0f / nrm : 1.0f;   // relu(nrm-1)+1 == max(nrm,1)
            float rp = 0.f;
#pragma unroll
            for (int rl = 0; rl < 4; rl++) {
                float s = 0.f;
                for (int ti = 0; ti < 32; ti++) {
                    m[rl][ti] *= sc;
                    s += m[rl][ti] * u2s[ti];
                }
                rp += u1s[rg * 4 + rl] * s;
            }
            red[rg][f] = rp;
            __syncthreads();
            float rv = 0.f;
#pragma unroll
            for (int g = 0; g < 8; g++) rv += red[g][f];
            float mean = rv;
            for (int mk = 1; mk < 32; mk <<= 1) mean += __shfl_xor(mean, mk, 32);
            mean *= (1.0f / 32.0f);
            float d = rv - mean;
            float var = d * d;
            for (int mk = 1; mk < 32; mk <<= 1) var += __shfl_xor(var, mk, 32);
            var *= (1.0f / 32.0f);
            if (tid < 32) {
                float y = d * rsqrtf(var + 1e-5f);
                llc_store_u16(acat + ((size_t)t * 64 + sb) * 544 + 512 + f, f2bf(y));
            }
            __syncthreads();
        }
    } else {
        // =================== persistent slot workers (blk 192..254) =======
        // 4096 MERGED units: m -> t = m>>3, s = m&7, rows t*64+s*8 .. +8.
        // kv phase shared between bind (NSLOT=3) and reas (NSLOT=2) passes.
        const int wid = blk - 192;   // 0..62
        stage_slot_weights(sm.s, tid, Wq, bq, Wk, bk, Wv, bv, lng, lnb,
                           Wm1, bm1, Wm2, bm2, Wsp, bsp);
        __syncthreads();
        int* myprog = prog + wid * 16;
        for (int mu = wid; mu < 4096; mu += 63) {
            const int t = mu >> 3, s = mu & 7;
            const size_t row0 = (size_t)t * 64 + s * 8;
            slot_kv(sm.s, tid, row0, dec);
            slot_pass<3>(sm.s, tid, row0, initb, r1, r2, fi);
            __syncthreads();   // pass-A reads of initl/slots done before restage
            slot_pass<2>(sm.s, tid, row0, initr, uu1, uu2, nullptr);
            __builtin_amdgcn_s_waitcnt(0);   // both passes' output stores acked
            __syncthreads();                 // all threads drained; LDS reusable
            if (tid == 0) ag_store(myprog, mu + 63);   // no pending unit < mu+63
        }
    }
}

// ---------------------------------------------------------------------------
extern "C" void kernel_launch(void* const* d_in, const int* in_sizes, int n_in,
                              void* d_out, int out_size, void* d_ws, size_t ws_size,
                              hipStream_t stream)
{
    (void)in_sizes; (void)n_in; (void)out_size; (void)ws_size;
    const int*   tokens = (const int*)d_in[0];
    const float* embW  = (const float*)d_in[1];
    const float* Wih0  = (const float*)d_in[2];
    const float* Whh0  = (const float*)d_in[3];
    const float* bih0  = (const float*)d_in[4];
    const float* bhh0  = (const float*)d_in[5];
    const float* Wih1  = (const float*)d_in[6];
    const float* Whh1  = (const float*)d_in[7];
    const float* bih1  = (const float*)d_in[8];
    const float* bhh1  = (const float*)d_in[9];
    const float* Wpi   = (const float*)d_in[10];
    const float* bpi   = (const float*)d_in[11];
    const float* Wq    = (const float*)d_in[12];
    const float* bq    = (const float*)d_in[13];
    const float* Wk    = (const float*)d_in[14];
    const float* bk    = (const float*)d_in[15];
    const float* Wv    = (const float*)d_in[16];
    const float* bv    = (const float*)d_in[17];
    const float* lng   = (const float*)d_in[18];
    const float* lnb   = (const float*)d_in[19];
    const float* Wm1   = (const float*)d_in[20];
    const float* bm1   = (const float*)d_in[21];
    const float* Wm2   = (const float*)d_in[22];
    const float* bm2   = (const float*)d_in[23];
    const float* Wbind = (const float*)d_in[24];
    const float* bbind = (const float*)d_in[25];
    const float* Wreas = (const float*)d_in[26];
    const float* breas = (const float*)d_in[27];
    const float* Wsp   = (const float*)d_in[28];
    const float* bsp   = (const float*)d_in[29];
    const float* Wg    = (const float*)d_in[30];
    const float* bg    = (const float*)d_in[31];
    const float* Wout  = (const float*)d_in[32];
    const float* bout  = (const float*)d_in[33];

    char* ws = (char*)d_ws;
    size_t off = 0;
    auto alloc = [&](size_t bytes) { size_t o = off; off += (bytes + 255) & ~(size_t)255; return o; };
    int*  flags  = (int*)(ws + alloc(16384 * 4));   // f0, f1, f1s, prog
    u16*  emb    = (u16*)(ws + alloc(32768ull * 256 * 2));
    u16*  dec    = (u16*)(ws + alloc(32768ull * 192 * 2));
    u16*  initb  = (u16*)(ws + alloc(32768ull * 96 * 2));
    u16*  initr  = (u16*)(ws + alloc(32768ull * 64 * 2));
    u16*  acat   = (u16*)(ws + alloc(32768ull * 544 * 2));
    u16*  h0seq  = (u16*)(ws + alloc(512ull * 64 * 512 * 2));
    u16*  h1seq  = (u16*)(ws + alloc(512ull * 64 * 512 * 2));
    float* role1 = (float*)(ws + alloc(32768ull * 32 * 4));
    float* role2 = (float*)(ws + alloc(32768ull * 32 * 4));
    float* fill  = (float*)(ws + alloc(32768ull * 32 * 4));
    float* u1v   = (float*)(ws + alloc(32768ull * 32 * 4));
    float* u2v   = (float*)(ws + alloc(32768ull * 32 * 4));
    u16* Wx0b  = (u16*)(ws + alloc(2048ull * 256 * 2));
    u16* Wh0b  = (u16*)(ws + alloc(2048ull * 512 * 2));
    u16* Wx1b  = (u16*)(ws + alloc(2048ull * 512 * 2));
    u16* Wh1b  = (u16*)(ws + alloc(2048ull * 512 * 2));
    u16* Wpib  = (u16*)(ws + alloc(192ull * 256 * 2));
    u16* Wbindb = (u16*)(ws + alloc(96ull * 192 * 2));
    u16* Wreasb = (u16*)(ws + alloc(64ull * 192 * 2));
    u16* Woutb  = (u16*)(ws + alloc(128ull * 544 * 2));

    hipMemsetAsync(flags, 0, 16384 * 4, stream);
    {
        Cvt8 c;
        const float* s[8] = {Wih0, Whh0, Wih1, Whh1, Wpi, Wbind, Wreas, Wout};
        u16* d[8] = {Wx0b, Wh0b, Wx1b, Wh1b, Wpib, Wbindb, Wreasb, Woutb};
        int n[8] = {2048 * 256, 2048 * 512, 2048 * 512, 2048 * 512,
                    192 * 256, 96 * 192, 64 * 192, 128 * 544};
        int acc = 0;
        for (int k = 0; k < 8; k++) { c.s[k] = s[k]; c.d[k] = d[k]; c.off4[k] = acc; acc += n[k] / 4; }
        c.off4[8] = acc;
        k_f2b8<<<(acc + 255) / 256, 256, 0, stream>>>(c);
    }
    k_embed<<<4096, 256, 0, stream>>>(tokens, embW, emb);
    k_gemm_bt<<<dim3(256, 2), 256, 0, stream>>>(emb, 256, Wpib, dec, nullptr, 192, bpi, nullptr, 192, 256);
    k_gemm_bt<<<dim3(256, 1), 256, 0, stream>>>(dec, 192, Wbindb, initb, nullptr, 96, bbind, nullptr, 96, 192);
    k_gemm_bt<<<dim3(256, 1), 256, 0, stream>>>(dec, 192, Wreasb, initr, nullptr, 64, breas, nullptr, 64, 192);
    // fused: LSTM(2 layers) + scan/gate + merged bind/reas slot workers
    k_mega<<<255, 256, 0, stream>>>(emb, Wx0b, Wh0b, Wx1b, Wh1b,
                                    bih0, bhh0, bih1, bhh1,
                                    h0seq, h1seq, acat, flags,
                                    role1, role2, fill, u1v, u2v, Wg, bg,
                                    dec, initb, initr,
                                    Wq, bq, Wk, bk, Wv, bv, lng, lnb,
                                    Wm1, bm1, Wm2, bm2, Wsp, bsp);
    // out = acat @ Wout^T + bout  (fp32 output)
    k_gemm_bt<<<dim3(256, 1), 256, 0, stream>>>(acat, 544, Woutb, nullptr, (float*)d_out, 128, bout, nullptr, 128, 544);
}